// Round 7
// baseline (56.971 us; speedup 1.0000x reference)
//
#include <hip/hip_runtime.h>

#define NA 128   // agents per batch
#define NKN 16   // neighbours

typedef _Float16 f16;
typedef __fp16   h16x2 __attribute__((ext_vector_type(2)));   // cvt_pkrtz result type
typedef _Float16 f16x8 __attribute__((ext_vector_type(8)));
typedef float    f32x16 __attribute__((ext_vector_type(16)));
typedef unsigned long long u64;

#define MFMA __builtin_amdgcn_mfma_f32_32x32x16_f16
// 256B-row f16 matrices: XOR row bits into the 16B-slot index -> 16 slots, 2-way (free)
#define SWZ16(row, byteoff) ((byteoff) ^ (((row)&15)<<4))
// 64B-row f16 matrices (X, W1T): 4 slots
#define SWZ4(row, byteoff)  ((byteoff) ^ (((row)&3)<<4))
// candidate-slot swizzle: u64 slot l of agent ia -> spread 16 agents across banks
#define CSW(ia, l) ((l) ^ (((ia) & 15) << 1))

__device__ __forceinline__ float tanh_fast(float x){
    float e = __expf(2.f * x);
    return 1.f - 2.f * __builtin_amdgcn_rcpf(e + 1.f);
}

__device__ __forceinline__ unsigned int wsel(const uint4 c, int i){ // i compile-time
    return i==0 ? c.x : i==1 ? c.y : i==2 ? c.z : c.w;
}

// 16-wave agg matmul: wave (rb,cb) computes OUT[h=rb*32..][j=cb*32..] 32x32 tile,
// OUT[h][j] = sum_i IN[h][i]*M[i][j] (M incl. diagonal from cmask bits);
// epilogue X = tanh(d_j*OUT + bias[h]) stored transposed to matOut[j][h].
__device__ __forceinline__ void agg_mm(const unsigned char* matIn, unsigned char* matOut,
                                       const unsigned int (*cmask)[4], const float* dinv_s,
                                       const float* bias, const u64* lut,
                                       int wv, int lane)
{
    const int lr = lane & 31, lg = lane >> 5;
    const int rb = wv & 3, cb = wv >> 2;
    f32x16 c0;
    #pragma unroll
    for (int e = 0; e < 16; ++e) c0[e] = 0.f;

    const int j = cb*32 + lr;
    const uint4 cm = *(const uint4*)&cmask[j][0];
    const int row = rb*32 + lr;   // h

    #pragma unroll
    for (int ks = 0; ks < 8; ++ks) {
        f16x8 af = *(const f16x8*)(matIn + row*256 + SWZ16(row, ks*32 + lg*16));
        const int sh = (ks&1)*16 + lg*8;
        const unsigned int bb = (wsel(cm, ks>>1) >> sh) & 0xFFu;
        union { f16x8 v; u64 u[2]; } B0;
        B0.u[0] = lut[bb & 15u]; B0.u[1] = lut[bb >> 4];
        c0 = MFMA(af, B0.v, c0, 0, 0, 0);
    }
    const float dj = dinv_s[j];
    #pragma unroll
    for (int q = 0; q < 4; ++q) {
        const int r0 = rb*32 + q*8 + lg*4;   // h quad
        const float4 bv = *(const float4*)&bias[r0];
        const float v0 = tanh_fast(fmaf(dj, c0[q*4+0], bv.x));
        const float v1 = tanh_fast(fmaf(dj, c0[q*4+1], bv.y));
        const float v2 = tanh_fast(fmaf(dj, c0[q*4+2], bv.z));
        const float v3 = tanh_fast(fmaf(dj, c0[q*4+3], bv.w));
        union { h16x2 h[2]; u64 u; } pk;
        pk.h[0] = __builtin_amdgcn_cvt_pkrtz(v0, v1);
        pk.h[1] = __builtin_amdgcn_cvt_pkrtz(v2, v3);
        *(u64*)(matOut + j*256 + SWZ16(j, r0*2)) = pk.u;
    }
}

// prep: pre-transposed + pre-swizzled f16 images of W1^T [128][32] and W2^T [128][128]
__global__ __launch_bounds__(512, 1) void prep(const float* __restrict__ W1g,
                                               const float* __restrict__ W2g,
                                               unsigned char* __restrict__ ws)
{
    const int m = blockIdx.x * 512 + threadIdx.x;   // grid 5 -> 2560 tiles
    if (m < 2048) {                                  // W2T tiles: 128 h2 x 16 k-groups
        const int h2 = m & 127, g = m >> 7;
        f16x8 v;
        #pragma unroll
        for (int s = 0; s < 8; ++s) v[s] = (f16)W2g[(g*8 + s)*128 + h2];
        *(f16x8*)(ws + 8192 + h2*256 + SWZ16(h2, g*16)) = v;
    } else {                                         // W1T tiles: 128 h x 4 k-groups
        const int m2 = m - 2048;
        const int h = m2 & 127, g = m2 >> 7;
        f16x8 v;
        #pragma unroll
        for (int s = 0; s < 8; ++s) v[s] = (f16)W1g[(g*8 + s)*128 + h];
        *(f16x8*)(ws + h*64 + SWZ4(h, g*16)) = v;
    }
}

__global__ __launch_bounds__(1024, 8) void gnn_fused(
    const float* __restrict__ obs,
    const unsigned char* __restrict__ ws,     // prep images
    const float* __restrict__ b1g, const float* __restrict__ b2g,
    const float* __restrict__ Wog, const float* __restrict__ bog,
    float* __restrict__ outg)
{
    __shared__ __align__(16) unsigned char mat0[32768]; // cand -> W1T -> G1 -> W2T -> X3
    __shared__ __align__(16) unsigned char mat1[32768]; // Xf16(8K) -> X2 -> G2
    __shared__ float posx[NA], posy[NA], dinv_s[NA], b1s[NA], b2s[NA], wos[NA];
    __shared__ unsigned int cmask[NA][4];
    __shared__ unsigned int ccnt[NA];
    __shared__ u64 lut16[16];

    const int t = threadIdx.x;
    const int b = blockIdx.x;
    const int wv = t >> 6, lane = t & 63;
    const int lr = lane & 31, lg = lane >> 5;

    // ---- phase 0: stage obs->Xf16 (+pos), params, cmask diag, LUT, cand init ----
    {
        const float4* ob = (const float4*)(obs + (size_t)b * NA * 32);
        {
            const int i = t >> 3, seg = t & 7;     // 1024 float4 = [128 i][8 seg]
            const float4 v = ob[t];
            if (seg == 0) { posx[i] = v.x; posy[i] = v.y; }
            union { h16x2 h[2]; u64 u; } pk;
            pk.h[0] = __builtin_amdgcn_cvt_pkrtz(v.x, v.y);
            pk.h[1] = __builtin_amdgcn_cvt_pkrtz(v.z, v.w);
            *(u64*)(mat1 + i*64 + SWZ4(i, seg*8)) = pk.u;
        }
        u64* cand = (u64*)mat0;                    // 4096 u64 slots = 128 agents x 32
        #pragma unroll
        for (int s = 0; s < 4; ++s) cand[t*4 + s] = ~0ull;
        if (t < NA) { b1s[t] = b1g[t]; b2s[t] = b2g[t]; wos[t] = Wog[t]; ccnt[t] = 0u; }
        if (t < 512) { const int j = t >> 2, w = t & 3; cmask[j][w] = (w == (j>>5)) ? (1u << (j&31)) : 0u; }
        if (t < 16) {
            u64 e = 0ull;
            #pragma unroll
            for (int s = 0; s < 4; ++s)
                if ((t >> s) & 1) e |= 0x3C00ull << (16*s);   // f16 1.0
            lut16[t] = e;
        }
    }
    __syncthreads();

    // ---- phase 1: exact kNN via pivot-bisection + candidate ranking (8 lanes/agent) ----
    const int ia = t >> 3, p8 = t & 7;
    {
        u64* cand = (u64*)mat0;
        // 1a: distance bit-keys (bit-exact vs ref: rn mul/add, rn sqrt; monotone u32)
        unsigned int kd[16];
        const float xi = posx[ia], yi = posy[ia];
        #pragma unroll
        for (int jj = 0; jj < 16; ++jj) {
            const int j = p8*16 + jj;
            const float dx = __fsub_rn(xi, posx[j]);
            const float dy = __fsub_rn(yi, posy[j]);
            const float d  = __fsqrt_rn(__fadd_rn(__fmul_rn(dx,dx), __fmul_rn(dy,dy)));
            kd[jj] = __float_as_uint(d);         // self: exactly 0
        }
        // 1b: bisect pivot P until 17 <= count(kd < P) <= 32 (wide window: ~3-6 iters)
        unsigned int lo = 0u, hi = 0xFF000000u, P = 0u;
        bool done = false;
        #pragma unroll 1
        for (int it = 0; it < 34; ++it) {
            const unsigned int mid = (lo + hi) >> 1;
            int cl = 0;
            #pragma unroll
            for (int jj = 0; jj < 16; ++jj) cl += (kd[jj] < mid) ? 1 : 0;
            cl += __shfl_xor(cl, 1, 64);
            cl += __shfl_xor(cl, 2, 64);
            cl += __shfl_xor(cl, 4, 64);
            if (!done) {
                if (cl >= 17 && cl <= 32) { P = mid; done = true; }
                else if (cl < 17) lo = mid;
                else hi = mid;
                if (hi - lo <= 1u && !done) { P = hi; done = true; }
            }
            if (__all(done ? 1 : 0)) break;
        }
        if (!done) P = hi;
        // 1c: compact candidates (dbits<<32|idx) into swizzled LDS slots
        #pragma unroll
        for (int jj = 0; jj < 16; ++jj) {
            if (kd[jj] < P) {
                const unsigned int s = atomicAdd(&ccnt[ia], 1u);
                if (s < 32u)
                    cand[ia*32 + CSW(ia, s)] = ((u64)kd[jj] << 32) | (unsigned)(p8*16 + jj);
            }
        }
    }
    __syncthreads();
    {
        const u64* cand = (const u64*)mat0;
        // 1d: rank among candidates (exact (dist,idx) lexicographic order).
        // rank r in [1,16] => neighbor (rank 0 = the dropped first top_k entry, exactly
        // matching top_k(-d,17)[1:] incl. duplicate-position degeneracy).
        // STATIC register indexing only (rule #20): lane owns 4 candidates in ck4[q];
        // the 32 keys stream from LDS (broadcast reads).
        u64 ck4[4];
        int rk[4];
        #pragma unroll
        for (int q = 0; q < 4; ++q) {
            ck4[q] = cand[ia*32 + CSW(ia, 4*p8 + q)];
            rk[q] = 0;
        }
        #pragma unroll
        for (int e = 0; e < 32; ++e) {
            const u64 ke = cand[ia*32 + CSW(ia, e)];
            #pragma unroll
            for (int q = 0; q < 4; ++q) rk[q] += (ke < ck4[q]) ? 1 : 0;
        }
        const int m = (int)min(ccnt[ia], 32u);
        #pragma unroll
        for (int q = 0; q < 4; ++q) {
            const int c = 4*p8 + q;
            if (c < m && rk[q] >= 1 && rk[q] < 17) {
                const int n = (int)(ck4[q] & 127u);
                atomicOr(&cmask[n][ia >> 5], 1u << (ia & 31));
            }
        }
    }
    __syncthreads();
    // ---- phase 1e: degrees + stage W1T image into mat0 (overwrites cand) ----
    if (t < NA)
        dinv_s[t] = rsqrtf((float)(__popc(cmask[t][0]) + __popc(cmask[t][1]) +
                                   __popc(cmask[t][2]) + __popc(cmask[t][3])));
    if (t < 512) *(f16x8*)(mat0 + t*16) = *(const f16x8*)(ws + t*16);   // W1T 8KB verbatim
    __syncthreads();

    // ---- phase 2: conv1  G1[h][i] = d_i*(X@W1)[i][h]; wave (rb,cb): i-block rb, h-block cb ----
    {
        f32x16 c0;
        #pragma unroll
        for (int e = 0; e < 16; ++e) c0[e] = 0.f;
        const int rb = wv & 3, cb = wv >> 2;
        const int row = rb*32 + lr;              // node i
        const int h = cb*32 + lr;
        #pragma unroll
        for (int ks = 0; ks < 2; ++ks) {
            const f16x8 af = *(const f16x8*)(mat1 + row*64 + SWZ4(row, ks*32 + lg*16));
            const f16x8 bf = *(const f16x8*)(mat0 + h*64 + SWZ4(h, ks*32 + lg*16));
            c0 = MFMA(af, bf, c0, 0, 0, 0);
        }
        __syncthreads();   // all W1T reads done before G1 overwrites mat0
        #pragma unroll
        for (int q = 0; q < 4; ++q) {
            const int r0 = rb*32 + q*8 + lg*4;   // node quad
            const float4 dv = *(const float4*)&dinv_s[r0];
            union { h16x2 hh[2]; u64 u; } pk;
            pk.hh[0] = __builtin_amdgcn_cvt_pkrtz(c0[q*4+0]*dv.x, c0[q*4+1]*dv.y);
            pk.hh[1] = __builtin_amdgcn_cvt_pkrtz(c0[q*4+2]*dv.z, c0[q*4+3]*dv.w);
            *(u64*)(mat0 + h*256 + SWZ16(h, r0*2)) = pk.u;
        }
    }
    __syncthreads();

    // ---- phase 3: agg1 -> X2[j][h] in mat1 (overwrites consumed X image) ----
    agg_mm(mat0, mat1, cmask, dinv_s, b1s, lut16, wv, lane);
    __syncthreads();

    // ---- phase 4: stage W2T image (verbatim), then conv2 -> G2[h2][j] ----
    {
        #pragma unroll
        for (int rep = 0; rep < 2; ++rep) {
            const int idx = rep*1024 + t;
            *(f16x8*)(mat0 + idx*16) = *(const f16x8*)(ws + 8192 + idx*16);
        }
    }
    __syncthreads();
    {
        f32x16 c0;
        #pragma unroll
        for (int e = 0; e < 16; ++e) c0[e] = 0.f;
        const int rb = wv & 3, cb = wv >> 2;
        const int row = rb*32 + lr;              // j
        const int h2 = cb*32 + lr;
        #pragma unroll
        for (int ks = 0; ks < 8; ++ks) {
            const f16x8 af = *(const f16x8*)(mat1 + row*256 + SWZ16(row, ks*32 + lg*16));
            const f16x8 bf = *(const f16x8*)(mat0 + h2*256 + SWZ16(h2, ks*32 + lg*16));
            c0 = MFMA(af, bf, c0, 0, 0, 0);
        }
        __syncthreads();   // X2 reads done before G2 overwrites mat1
        #pragma unroll
        for (int q = 0; q < 4; ++q) {
            const int r0 = rb*32 + q*8 + lg*4;   // j quad
            const float4 dv = *(const float4*)&dinv_s[r0];
            union { h16x2 hh[2]; u64 u; } pk;
            pk.hh[0] = __builtin_amdgcn_cvt_pkrtz(c0[q*4+0]*dv.x, c0[q*4+1]*dv.y);
            pk.hh[1] = __builtin_amdgcn_cvt_pkrtz(c0[q*4+2]*dv.z, c0[q*4+3]*dv.w);
            *(u64*)(mat1 + h2*256 + SWZ16(h2, r0*2)) = pk.u;
        }
    }
    __syncthreads();

    // ---- phase 5: agg2 -> X3[j][h2] in mat0 (overwrites W2T image) ----
    agg_mm(mat1, mat0, cmask, dinv_s, b2s, lut16, wv, lane);
    __syncthreads();

    // ---- phase 6: head out[j] = X3[j].wo + bout (8 lanes/agent) ----
    {
        float s = 0.f;
        #pragma unroll
        for (int u = 0; u < 2; ++u) {
            const f16x8 v = *(const f16x8*)(mat0 + ia*256 + SWZ16(ia, p8*32 + u*16));
            const float4 w0 = *(const float4*)&wos[p8*16 + u*8];
            const float4 w1 = *(const float4*)&wos[p8*16 + u*8 + 4];
            s = fmaf((float)v[0], w0.x, s); s = fmaf((float)v[1], w0.y, s);
            s = fmaf((float)v[2], w0.z, s); s = fmaf((float)v[3], w0.w, s);
            s = fmaf((float)v[4], w1.x, s); s = fmaf((float)v[5], w1.y, s);
            s = fmaf((float)v[6], w1.z, s); s = fmaf((float)v[7], w1.w, s);
        }
        s += __shfl_xor(s, 1, 64);
        s += __shfl_xor(s, 2, 64);
        s += __shfl_xor(s, 4, 64);
        if (p8 == 0) outg[b*NA + ia] = s + bog[0];
    }
}

extern "C" void kernel_launch(void* const* d_in, const int* in_sizes, int n_in,
                              void* d_out, int out_size, void* d_ws, size_t ws_size,
                              hipStream_t stream) {
    const float* obs = (const float*)d_in[0];
    const float* W1  = (const float*)d_in[1];
    const float* b1  = (const float*)d_in[2];
    const float* W2  = (const float*)d_in[3];
    const float* b2  = (const float*)d_in[4];
    const float* Wo  = (const float*)d_in[5];
    const float* bo  = (const float*)d_in[6];
    float* out = (float*)d_out;
    const int B = in_sizes[0] / (NA * 32);
    unsigned char* ws = (unsigned char*)d_ws;   // needs 40 KB: W1T(8K) + W2T(32K)
    hipLaunchKernelGGL(prep, dim3(5), dim3(512), 0, stream, W1, W2, ws);
    hipLaunchKernelGGL(gnn_fused, dim3(B), dim3(1024), 0, stream,
                       obs, ws, b1, b2, Wo, bo, out);
}

// Round 8
// 44.699 us; speedup vs baseline: 1.2746x; 1.2746x over previous
//
#include <hip/hip_runtime.h>

#define NA 128   // agents per batch
#define NKN 16   // neighbours

typedef _Float16 f16;
typedef __fp16   h16x2 __attribute__((ext_vector_type(2)));   // cvt_pkrtz result type
typedef _Float16 f16x8 __attribute__((ext_vector_type(8)));
typedef float    f32x16 __attribute__((ext_vector_type(16)));
typedef unsigned long long u64;

#define MFMA __builtin_amdgcn_mfma_f32_32x32x16_f16
// 256B-row f16 matrices: XOR row bits into the 16B-slot index -> 16 slots, 2-way (free)
#define SWZ16(row, byteoff) ((byteoff) ^ (((row)&15)<<4))
// 64B-row f16 matrices (X, W1T): 4 slots
#define SWZ4(row, byteoff)  ((byteoff) ^ (((row)&3)<<4))
// candidate-slot swizzle: u64 slot l of agent ia -> spread 16 agents across banks
#define CSW(ia, l) ((l) ^ (((ia) & 15) << 1))

__device__ __forceinline__ float tanh_fast(float x){
    float e = __expf(2.f * x);
    return 1.f - 2.f * __builtin_amdgcn_rcpf(e + 1.f);
}

__device__ __forceinline__ unsigned int wsel(const uint4 c, int i){ // i compile-time
    return i==0 ? c.x : i==1 ? c.y : i==2 ? c.z : c.w;
}

// 16-wave agg matmul: wave (rb,cb) computes OUT[h=rb*32..][j=cb*32..] 32x32 tile,
// OUT[h][j] = sum_i IN[h][i]*M[i][j] (M incl. diagonal from cmask bits);
// epilogue X = tanh(d_j*OUT + bias[h]) stored transposed to matOut[j][h].
__device__ __forceinline__ void agg_mm(const unsigned char* matIn, unsigned char* matOut,
                                       const unsigned int (*cmask)[4], const float* dinv_s,
                                       const float* bias, const u64* lut,
                                       int wv, int lane)
{
    const int lr = lane & 31, lg = lane >> 5;
    const int rb = wv & 3, cb = wv >> 2;
    f32x16 c0;
    #pragma unroll
    for (int e = 0; e < 16; ++e) c0[e] = 0.f;

    const int j = cb*32 + lr;
    const uint4 cm = *(const uint4*)&cmask[j][0];
    const int row = rb*32 + lr;   // h

    #pragma unroll
    for (int ks = 0; ks < 8; ++ks) {
        f16x8 af = *(const f16x8*)(matIn + row*256 + SWZ16(row, ks*32 + lg*16));
        const int sh = (ks&1)*16 + lg*8;
        const unsigned int bb = (wsel(cm, ks>>1) >> sh) & 0xFFu;
        union { f16x8 v; u64 u[2]; } B0;
        B0.u[0] = lut[bb & 15u]; B0.u[1] = lut[bb >> 4];
        c0 = MFMA(af, B0.v, c0, 0, 0, 0);
    }
    const float dj = dinv_s[j];
    #pragma unroll
    for (int q = 0; q < 4; ++q) {
        const int r0 = rb*32 + q*8 + lg*4;   // h quad
        const float4 bv = *(const float4*)&bias[r0];
        const float v0 = tanh_fast(fmaf(dj, c0[q*4+0], bv.x));
        const float v1 = tanh_fast(fmaf(dj, c0[q*4+1], bv.y));
        const float v2 = tanh_fast(fmaf(dj, c0[q*4+2], bv.z));
        const float v3 = tanh_fast(fmaf(dj, c0[q*4+3], bv.w));
        union { h16x2 h[2]; u64 u; } pk;
        pk.h[0] = __builtin_amdgcn_cvt_pkrtz(v0, v1);
        pk.h[1] = __builtin_amdgcn_cvt_pkrtz(v2, v3);
        *(u64*)(matOut + j*256 + SWZ16(j, r0*2)) = pk.u;
    }
}

// prep: pre-transposed + pre-swizzled f16 images of W1^T [128][32] and W2^T [128][128]
__global__ __launch_bounds__(512, 1) void prep(const float* __restrict__ W1g,
                                               const float* __restrict__ W2g,
                                               unsigned char* __restrict__ ws)
{
    const int m = blockIdx.x * 512 + threadIdx.x;   // grid 5 -> 2560 tiles
    if (m < 2048) {                                  // W2T tiles: 128 h2 x 16 k-groups
        const int h2 = m & 127, g = m >> 7;
        f16x8 v;
        #pragma unroll
        for (int s = 0; s < 8; ++s) v[s] = (f16)W2g[(g*8 + s)*128 + h2];
        *(f16x8*)(ws + 8192 + h2*256 + SWZ16(h2, g*16)) = v;
    } else {                                         // W1T tiles: 128 h x 4 k-groups
        const int m2 = m - 2048;
        const int h = m2 & 127, g = m2 >> 7;
        f16x8 v;
        #pragma unroll
        for (int s = 0; s < 8; ++s) v[s] = (f16)W1g[(g*8 + s)*128 + h];
        *(f16x8*)(ws + h*64 + SWZ4(h, g*16)) = v;
    }
}

__global__ __launch_bounds__(1024, 4) void gnn_fused(
    const float* __restrict__ obs,
    const unsigned char* __restrict__ ws,     // prep images
    const float* __restrict__ b1g, const float* __restrict__ b2g,
    const float* __restrict__ Wog, const float* __restrict__ bog,
    float* __restrict__ outg)
{
    __shared__ __align__(16) unsigned char mat0[32768]; // cand -> W1T -> G1 -> W2T -> X3
    __shared__ __align__(16) unsigned char mat1[32768]; // Xf16(8K) -> X2 -> G2
    __shared__ float posx[NA], posy[NA], dinv_s[NA], b1s[NA], b2s[NA], wos[NA];
    __shared__ unsigned int cmask[NA][4];
    __shared__ unsigned int ccnt[NA];
    __shared__ u64 lut16[16];

    const int t = threadIdx.x;
    const int b = blockIdx.x;
    const int wv = t >> 6, lane = t & 63;
    const int lr = lane & 31, lg = lane >> 5;

    // ---- phase 0: stage obs->Xf16 (+pos), params, cmask diag, LUT, cand init ----
    {
        const float4* ob = (const float4*)(obs + (size_t)b * NA * 32);
        {
            const int i = t >> 3, seg = t & 7;     // 1024 float4 = [128 i][8 seg]
            const float4 v = ob[t];
            if (seg == 0) { posx[i] = v.x; posy[i] = v.y; }
            union { h16x2 h[2]; u64 u; } pk;
            pk.h[0] = __builtin_amdgcn_cvt_pkrtz(v.x, v.y);
            pk.h[1] = __builtin_amdgcn_cvt_pkrtz(v.z, v.w);
            *(u64*)(mat1 + i*64 + SWZ4(i, seg*8)) = pk.u;
        }
        u64* cand = (u64*)mat0;                    // 4096 u64 slots = 128 agents x 32
        #pragma unroll
        for (int s = 0; s < 4; ++s) cand[t*4 + s] = ~0ull;
        if (t < NA) { b1s[t] = b1g[t]; b2s[t] = b2g[t]; wos[t] = Wog[t]; ccnt[t] = 0u; }
        if (t < 512) { const int j = t >> 2, w = t & 3; cmask[j][w] = (w == (j>>5)) ? (1u << (j&31)) : 0u; }
        if (t < 16) {
            u64 e = 0ull;
            #pragma unroll
            for (int s = 0; s < 4; ++s)
                if ((t >> s) & 1) e |= 0x3C00ull << (16*s);   // f16 1.0
            lut16[t] = e;
        }
    }
    __syncthreads();

    // ---- phase 1: exact kNN via pivot-bisection + candidate ranking (8 lanes/agent) ----
    const int ia = t >> 3, p8 = t & 7;
    {
        u64* cand = (u64*)mat0;
        // 1a: distance bit-keys (bit-exact vs ref: rn mul/add, rn sqrt; monotone u32)
        unsigned int kd[16];
        const float xi = posx[ia], yi = posy[ia];
        #pragma unroll
        for (int jj = 0; jj < 16; ++jj) {
            const int j = p8*16 + jj;
            const float dx = __fsub_rn(xi, posx[j]);
            const float dy = __fsub_rn(yi, posy[j]);
            const float d  = __fsqrt_rn(__fadd_rn(__fmul_rn(dx,dx), __fmul_rn(dy,dy)));
            kd[jj] = __float_as_uint(d);         // self: exactly 0
        }
        // 1b: bisect pivot P until 17 <= count(kd < P) <= 32 (wide window: ~3-6 iters)
        unsigned int lo = 0u, hi = 0xFF000000u, P = 0u;
        bool done = false;
        #pragma unroll 1
        for (int it = 0; it < 34; ++it) {
            const unsigned int mid = (lo + hi) >> 1;
            int cl = 0;
            #pragma unroll
            for (int jj = 0; jj < 16; ++jj) cl += (kd[jj] < mid) ? 1 : 0;
            cl += __shfl_xor(cl, 1, 64);
            cl += __shfl_xor(cl, 2, 64);
            cl += __shfl_xor(cl, 4, 64);
            if (!done) {
                if (cl >= 17 && cl <= 32) { P = mid; done = true; }
                else if (cl < 17) lo = mid;
                else hi = mid;
                if (hi - lo <= 1u && !done) { P = hi; done = true; }
            }
            if (__all(done ? 1 : 0)) break;
        }
        if (!done) P = hi;
        // 1c: compact candidates (dbits<<32|idx) into swizzled LDS slots
        #pragma unroll
        for (int jj = 0; jj < 16; ++jj) {
            if (kd[jj] < P) {
                const unsigned int s = atomicAdd(&ccnt[ia], 1u);
                if (s < 32u)
                    cand[ia*32 + CSW(ia, s)] = ((u64)kd[jj] << 32) | (unsigned)(p8*16 + jj);
            }
        }
    }
    __syncthreads();
    {
        const u64* cand = (const u64*)mat0;
        // 1d: rank among candidates (exact (dist,idx) lexicographic order).
        // rank r in [1,16] => neighbor (rank 0 = the dropped first top_k entry, exactly
        // matching top_k(-d,17)[1:] incl. duplicate-position degeneracy).
        // STATIC register indexing only (rule #20): lane owns 4 candidates in ck4[q];
        // the 32 keys stream from LDS (broadcast reads).
        u64 ck4[4];
        int rk[4];
        #pragma unroll
        for (int q = 0; q < 4; ++q) {
            ck4[q] = cand[ia*32 + CSW(ia, 4*p8 + q)];
            rk[q] = 0;
        }
        #pragma unroll
        for (int e = 0; e < 32; ++e) {
            const u64 ke = cand[ia*32 + CSW(ia, e)];
            #pragma unroll
            for (int q = 0; q < 4; ++q) rk[q] += (ke < ck4[q]) ? 1 : 0;
        }
        const int m = (int)min(ccnt[ia], 32u);
        #pragma unroll
        for (int q = 0; q < 4; ++q) {
            const int c = 4*p8 + q;
            if (c < m && rk[q] >= 1 && rk[q] < 17) {
                const int n = (int)(ck4[q] & 127u);
                atomicOr(&cmask[n][ia >> 5], 1u << (ia & 31));
            }
        }
    }
    __syncthreads();
    // ---- phase 1e: degrees + stage W1T image into mat0 (overwrites cand) ----
    if (t < NA)
        dinv_s[t] = rsqrtf((float)(__popc(cmask[t][0]) + __popc(cmask[t][1]) +
                                   __popc(cmask[t][2]) + __popc(cmask[t][3])));
    if (t < 512) *(f16x8*)(mat0 + t*16) = *(const f16x8*)(ws + t*16);   // W1T 8KB verbatim
    __syncthreads();

    // ---- phase 2: conv1  G1[h][i] = d_i*(X@W1)[i][h]; wave (rb,cb): i-block rb, h-block cb ----
    {
        f32x16 c0;
        #pragma unroll
        for (int e = 0; e < 16; ++e) c0[e] = 0.f;
        const int rb = wv & 3, cb = wv >> 2;
        const int row = rb*32 + lr;              // node i
        const int h = cb*32 + lr;
        #pragma unroll
        for (int ks = 0; ks < 2; ++ks) {
            const f16x8 af = *(const f16x8*)(mat1 + row*64 + SWZ4(row, ks*32 + lg*16));
            const f16x8 bf = *(const f16x8*)(mat0 + h*64 + SWZ4(h, ks*32 + lg*16));
            c0 = MFMA(af, bf, c0, 0, 0, 0);
        }
        __syncthreads();   // all W1T reads done before G1 overwrites mat0
        #pragma unroll
        for (int q = 0; q < 4; ++q) {
            const int r0 = rb*32 + q*8 + lg*4;   // node quad
            const float4 dv = *(const float4*)&dinv_s[r0];
            union { h16x2 hh[2]; u64 u; } pk;
            pk.hh[0] = __builtin_amdgcn_cvt_pkrtz(c0[q*4+0]*dv.x, c0[q*4+1]*dv.y);
            pk.hh[1] = __builtin_amdgcn_cvt_pkrtz(c0[q*4+2]*dv.z, c0[q*4+3]*dv.w);
            *(u64*)(mat0 + h*256 + SWZ16(h, r0*2)) = pk.u;
        }
    }
    __syncthreads();

    // ---- phase 3: agg1 -> X2[j][h] in mat1 (overwrites consumed X image) ----
    agg_mm(mat0, mat1, cmask, dinv_s, b1s, lut16, wv, lane);
    __syncthreads();

    // ---- phase 4: stage W2T image (verbatim), then conv2 -> G2[h2][j] ----
    {
        #pragma unroll
        for (int rep = 0; rep < 2; ++rep) {
            const int idx = rep*1024 + t;
            *(f16x8*)(mat0 + idx*16) = *(const f16x8*)(ws + 8192 + idx*16);
        }
    }
    __syncthreads();
    {
        f32x16 c0;
        #pragma unroll
        for (int e = 0; e < 16; ++e) c0[e] = 0.f;
        const int rb = wv & 3, cb = wv >> 2;
        const int row = rb*32 + lr;              // j
        const int h2 = cb*32 + lr;
        #pragma unroll
        for (int ks = 0; ks < 8; ++ks) {
            const f16x8 af = *(const f16x8*)(mat1 + row*256 + SWZ16(row, ks*32 + lg*16));
            const f16x8 bf = *(const f16x8*)(mat0 + h2*256 + SWZ16(h2, ks*32 + lg*16));
            c0 = MFMA(af, bf, c0, 0, 0, 0);
        }
        __syncthreads();   // X2 reads done before G2 overwrites mat1
        #pragma unroll
        for (int q = 0; q < 4; ++q) {
            const int r0 = rb*32 + q*8 + lg*4;   // j quad
            const float4 dv = *(const float4*)&dinv_s[r0];
            union { h16x2 hh[2]; u64 u; } pk;
            pk.hh[0] = __builtin_amdgcn_cvt_pkrtz(c0[q*4+0]*dv.x, c0[q*4+1]*dv.y);
            pk.hh[1] = __builtin_amdgcn_cvt_pkrtz(c0[q*4+2]*dv.z, c0[q*4+3]*dv.w);
            *(u64*)(mat1 + h2*256 + SWZ16(h2, r0*2)) = pk.u;
        }
    }
    __syncthreads();

    // ---- phase 5: agg2 -> X3[j][h2] in mat0 (overwrites W2T image) ----
    agg_mm(mat1, mat0, cmask, dinv_s, b2s, lut16, wv, lane);
    __syncthreads();

    // ---- phase 6: head out[j] = X3[j].wo + bout (8 lanes/agent) ----
    {
        float s = 0.f;
        #pragma unroll
        for (int u = 0; u < 2; ++u) {
            const f16x8 v = *(const f16x8*)(mat0 + ia*256 + SWZ16(ia, p8*32 + u*16));
            const float4 w0 = *(const float4*)&wos[p8*16 + u*8];
            const float4 w1 = *(const float4*)&wos[p8*16 + u*8 + 4];
            s = fmaf((float)v[0], w0.x, s); s = fmaf((float)v[1], w0.y, s);
            s = fmaf((float)v[2], w0.z, s); s = fmaf((float)v[3], w0.w, s);
            s = fmaf((float)v[4], w1.x, s); s = fmaf((float)v[5], w1.y, s);
            s = fmaf((float)v[6], w1.z, s); s = fmaf((float)v[7], w1.w, s);
        }
        s += __shfl_xor(s, 1, 64);
        s += __shfl_xor(s, 2, 64);
        s += __shfl_xor(s, 4, 64);
        if (p8 == 0) outg[b*NA + ia] = s + bog[0];
    }
}

extern "C" void kernel_launch(void* const* d_in, const int* in_sizes, int n_in,
                              void* d_out, int out_size, void* d_ws, size_t ws_size,
                              hipStream_t stream) {
    const float* obs = (const float*)d_in[0];
    const float* W1  = (const float*)d_in[1];
    const float* b1  = (const float*)d_in[2];
    const float* W2  = (const float*)d_in[3];
    const float* b2  = (const float*)d_in[4];
    const float* Wo  = (const float*)d_in[5];
    const float* bo  = (const float*)d_in[6];
    float* out = (float*)d_out;
    const int B = in_sizes[0] / (NA * 32);
    unsigned char* ws = (unsigned char*)d_ws;   // needs 40 KB: W1T(8K) + W2T(32K)
    hipLaunchKernelGGL(prep, dim3(5), dim3(512), 0, stream, W1, W2, ws);
    hipLaunchKernelGGL(gnn_fused, dim3(B), dim3(1024), 0, stream,
                       obs, ws, b1, b2, Wo, bo, out);
}

// Round 9
// 33.704 us; speedup vs baseline: 1.6903x; 1.3262x over previous
//
#include <hip/hip_runtime.h>

#define NA 128   // agents per batch
#define NKN 16   // neighbours

typedef _Float16 f16;
typedef __fp16   h16x2 __attribute__((ext_vector_type(2)));   // cvt_pkrtz result type
typedef _Float16 f16x8 __attribute__((ext_vector_type(8)));
typedef float    f32x16 __attribute__((ext_vector_type(16)));
typedef unsigned long long u64;

#define MFMA __builtin_amdgcn_mfma_f32_32x32x16_f16
// 256B-row f16 matrices: XOR row bits into the 16B-slot index -> 16 slots, 2-way (free)
#define SWZ16(row, byteoff) ((byteoff) ^ (((row)&15)<<4))
// 64B-row f16 matrices (X, W1T): 4 slots
#define SWZ4(row, byteoff)  ((byteoff) ^ (((row)&3)<<4))
// candidate-slot swizzle: u64 slot l of agent ia -> spread 16 agents across banks
#define CSW(ia, l) ((l) ^ (((ia) & 15) << 1))

__device__ __forceinline__ float tanh_fast(float x){
    float e = __expf(2.f * x);
    return 1.f - 2.f * __builtin_amdgcn_rcpf(e + 1.f);
}

__device__ __forceinline__ unsigned int wsel(const uint4 c, int i){ // i compile-time
    return i==0 ? c.x : i==1 ? c.y : i==2 ? c.z : c.w;
}

// OUT[h][j] = sum_i IN[h][i]*M[i][j] (M incl. diagonal); X = tanh(d_j*OUT + bias[h]) stored-T.
__device__ __forceinline__ void agg_mm(const unsigned char* matIn, unsigned char* matOut,
                                       const unsigned int (*cmask)[4], const float* dinv_s,
                                       const float* bias, const u64* lut,
                                       int wv, int lane)
{
    const int lr = lane & 31, lg = lane >> 5;
    const int rb = wv & 3, ch = wv >> 2;
    f32x16 c0, c1;
    #pragma unroll
    for (int e = 0; e < 16; ++e) { c0[e] = 0.f; c1[e] = 0.f; }

    const int j0 = ch*64 + lr, j1 = j0 + 32;
    const uint4 cm0 = *(const uint4*)&cmask[j0][0];
    const uint4 cm1 = *(const uint4*)&cmask[j1][0];
    const int row = rb*32 + lr;   // h

    __builtin_amdgcn_s_setprio(1);
    #pragma unroll
    for (int ks = 0; ks < 8; ++ks) {
        f16x8 af = *(const f16x8*)(matIn + row*256 + SWZ16(row, ks*32 + lg*16));
        const int sh = (ks&1)*16 + lg*8;
        const unsigned int b0 = (wsel(cm0, ks>>1) >> sh) & 0xFFu;
        const unsigned int b1 = (wsel(cm1, ks>>1) >> sh) & 0xFFu;
        union { f16x8 v; u64 u[2]; } B0, B1;
        B0.u[0] = lut[b0 & 15u]; B0.u[1] = lut[b0 >> 4];
        B1.u[0] = lut[b1 & 15u]; B1.u[1] = lut[b1 >> 4];
        c0 = MFMA(af, B0.v, c0, 0, 0, 0);
        c1 = MFMA(af, B1.v, c1, 0, 0, 0);
    }
    __builtin_amdgcn_s_setprio(0);
    #pragma unroll
    for (int ct = 0; ct < 2; ++ct) {
        const int j = ct ? j1 : j0;
        const float dj = dinv_s[j];
        #pragma unroll
        for (int q = 0; q < 4; ++q) {
            const int r0 = rb*32 + q*8 + lg*4;   // h quad
            const float4 bv = *(const float4*)&bias[r0];
            float v0, v1, v2, v3;
            if (ct == 0) {
                v0 = tanh_fast(fmaf(dj, c0[q*4+0], bv.x));
                v1 = tanh_fast(fmaf(dj, c0[q*4+1], bv.y));
                v2 = tanh_fast(fmaf(dj, c0[q*4+2], bv.z));
                v3 = tanh_fast(fmaf(dj, c0[q*4+3], bv.w));
            } else {
                v0 = tanh_fast(fmaf(dj, c1[q*4+0], bv.x));
                v1 = tanh_fast(fmaf(dj, c1[q*4+1], bv.y));
                v2 = tanh_fast(fmaf(dj, c1[q*4+2], bv.z));
                v3 = tanh_fast(fmaf(dj, c1[q*4+3], bv.w));
            }
            union { h16x2 h[2]; u64 u; } pk;
            pk.h[0] = __builtin_amdgcn_cvt_pkrtz(v0, v1);
            pk.h[1] = __builtin_amdgcn_cvt_pkrtz(v2, v3);
            *(u64*)(matOut + j*256 + SWZ16(j, r0*2)) = pk.u;
        }
    }
}

__global__ __launch_bounds__(512, 4) void gnn_fused(
    const float* __restrict__ obs,
    const float* __restrict__ W1g, const float* __restrict__ b1g,
    const float* __restrict__ W2g, const float* __restrict__ b2g,
    const float* __restrict__ Wog, const float* __restrict__ bog,
    float* __restrict__ outg)
{
    __shared__ __align__(16) unsigned char mat0[32768]; // cand -> W1T -> G1 -> W2T -> X3
    __shared__ __align__(16) unsigned char mat1[32768]; // Xf16(8K) -> X2 -> G2
    __shared__ float posx[NA], posy[NA], dinv_s[NA], b1s[NA], b2s[NA], wos[NA];
    __shared__ unsigned int cmask[NA][4];
    __shared__ unsigned int ccnt[NA];
    __shared__ u64 lut16[16];

    const int t = threadIdx.x;
    const int b = blockIdx.x;
    const int wv = t >> 6, lane = t & 63;
    const int lr = lane & 31, lg = lane >> 5;

    // ---- phase 0: stage obs->Xf16 (+pos), params, cmask diag, LUT, cand init ----
    {
        const float4* ob = (const float4*)(obs + (size_t)b * NA * 32);
        #pragma unroll
        for (int rep = 0; rep < 2; ++rep) {
            const int idx = rep*512 + t;         // 1024 float4 = [128 i][8 seg]
            const int i = idx >> 3, seg = idx & 7;
            const float4 v = ob[idx];
            if (seg == 0) { posx[i] = v.x; posy[i] = v.y; }
            union { h16x2 h[2]; u64 u; } pk;
            pk.h[0] = __builtin_amdgcn_cvt_pkrtz(v.x, v.y);
            pk.h[1] = __builtin_amdgcn_cvt_pkrtz(v.z, v.w);
            *(u64*)(mat1 + i*64 + SWZ4(i, seg*8)) = pk.u;
        }
        u64* cand = (u64*)mat0;                  // 4096 u64 slots = 128 agents x 32
        #pragma unroll
        for (int s = 0; s < 8; ++s) cand[t*8 + s] = ~0ull;
        if (t < NA) { b1s[t] = b1g[t]; b2s[t] = b2g[t]; wos[t] = Wog[t]; ccnt[t] = 0u; }
        { const int j = t >> 2, w = t & 3; cmask[j][w] = (w == (j>>5)) ? (1u << (j&31)) : 0u; }
        if (t < 16) {
            u64 e = 0ull;
            #pragma unroll
            for (int s = 0; s < 4; ++s)
                if ((t >> s) & 1) e |= 0x3C00ull << (16*s);   // f16 1.0
            lut16[t] = e;
        }
    }
    __syncthreads();

    // ---- phase 1: exact kNN via pivot-bisection + candidate ranking ----
    const int ia = t >> 2, p4 = t & 3;
    {
        u64* cand = (u64*)mat0;
        // 1a: distance bit-keys (bit-exact vs ref: rn mul/add, rn sqrt; monotone u32)
        unsigned int kd[32];
        const float xi = posx[ia], yi = posy[ia];
        #pragma unroll
        for (int jj = 0; jj < 32; ++jj) {
            const int j = p4*32 + jj;
            const float dx = __fsub_rn(xi, posx[j]);
            const float dy = __fsub_rn(yi, posy[j]);
            const float d  = __fsqrt_rn(__fadd_rn(__fmul_rn(dx,dx), __fmul_rn(dy,dy)));
            kd[jj] = __float_as_uint(d);         // self: exactly 0
        }
        // 1b: bisect pivot P until 17 <= count(kd < P) <= 32 (wide window: ~3-6 iters)
        unsigned int lo = 0u, hi = 0xFF000000u, P = 0u;
        bool done = false;
        #pragma unroll 1
        for (int it = 0; it < 34; ++it) {
            const unsigned int mid = (lo + hi) >> 1;
            int cl = 0;
            #pragma unroll
            for (int jj = 0; jj < 32; ++jj) cl += (kd[jj] < mid) ? 1 : 0;
            cl += __shfl_xor(cl, 1, 64);
            cl += __shfl_xor(cl, 2, 64);
            if (!done) {
                if (cl >= 17 && cl <= 32) { P = mid; done = true; }
                else if (cl < 17) lo = mid;
                else hi = mid;
                if (hi - lo <= 1u && !done) { P = hi; done = true; }
            }
            if (__all(done ? 1 : 0)) break;
        }
        if (!done) P = hi;
        // 1c: compact candidates (dbits<<32|idx) into swizzled LDS slots
        #pragma unroll
        for (int jj = 0; jj < 32; ++jj) {
            if (kd[jj] < P) {
                const unsigned int s = atomicAdd(&ccnt[ia], 1u);
                if (s < 32u)
                    cand[ia*32 + CSW(ia, s)] = ((u64)kd[jj] << 32) | (unsigned)(p4*32 + jj);
            }
        }
    }
    __syncthreads();
    {
        const u64* cand = (const u64*)mat0;
        // 1d: rank among candidates (exact (dist,idx) lexicographic order).
        // rank r in [1,16] => neighbor (rank 0 = the dropped first top_k entry, exactly
        // matching top_k(-d,17)[1:] incl. duplicate-position degeneracy).
        // STATIC register indexing only (rule #20): lane owns 8 candidates in ck8[q];
        // the 32 keys stream from LDS (broadcast reads).
        u64 ck8[8];
        int rk[8];
        #pragma unroll
        for (int q = 0; q < 8; ++q) {
            ck8[q] = cand[ia*32 + CSW(ia, 8*p4 + q)];
            rk[q] = 0;
        }
        #pragma unroll
        for (int e = 0; e < 32; ++e) {
            const u64 ke = cand[ia*32 + CSW(ia, e)];
            #pragma unroll
            for (int q = 0; q < 8; ++q) rk[q] += (ke < ck8[q]) ? 1 : 0;
        }
        const int m = (int)min(ccnt[ia], 32u);
        #pragma unroll
        for (int q = 0; q < 8; ++q) {
            const int c = 8*p4 + q;
            if (c < m && rk[q] >= 1 && rk[q] < 17) {
                const int n = (int)(ck8[q] & 127u);
                atomicOr(&cmask[n][ia >> 5], 1u << (ia & 31));
            }
        }
    }
    __syncthreads();
    // ---- phase 1e: degrees + build W1T f16 image in mat0 (overwrites cand) ----
    if (t < NA)
        dinv_s[t] = rsqrtf((float)(__popc(cmask[t][0]) + __popc(cmask[t][1]) +
                                   __popc(cmask[t][2]) + __popc(cmask[t][3])));
    {   // W1T tile per thread: h = t&127, g = t>>7; v[s] = W1[(g*8+s)][h] (coalesced over h)
        const int h = t & 127, g = t >> 7;
        f16x8 v;
        #pragma unroll
        for (int s = 0; s < 8; ++s) v[s] = (f16)W1g[(g*8 + s)*128 + h];   // RTN cvt
        *(f16x8*)(mat0 + h*64 + SWZ4(h, g*16)) = v;
    }
    __syncthreads();

    // ---- phase 2: conv1  G1[h][i] = d_i*(X@W1)[i][h]  (A=Xf16, B=W1T, 16B frags) ----
    {
        f32x16 c0, c1;
        #pragma unroll
        for (int e = 0; e < 16; ++e) { c0[e] = 0.f; c1[e] = 0.f; }
        const int rb = wv & 3, ch = wv >> 2;
        const int row = rb*32 + lr;              // node i
        #pragma unroll
        for (int ks = 0; ks < 2; ++ks) {
            const f16x8 af = *(const f16x8*)(mat1 + row*64 + SWZ4(row, ks*32 + lg*16));
            #pragma unroll
            for (int ct = 0; ct < 2; ++ct) {
                const int h = ch*64 + ct*32 + lr;
                const f16x8 bf = *(const f16x8*)(mat0 + h*64 + SWZ4(h, ks*32 + lg*16));
                if (ct == 0) c0 = MFMA(af, bf, c0, 0, 0, 0);
                else         c1 = MFMA(af, bf, c1, 0, 0, 0);
            }
        }
        __syncthreads();   // all W1T/X reads done before G1 overwrites mat0
        #pragma unroll
        for (int ct = 0; ct < 2; ++ct) {
            const int h = ch*64 + ct*32 + lr;
            #pragma unroll
            for (int q = 0; q < 4; ++q) {
                const int r0 = rb*32 + q*8 + lg*4;   // node quad
                const float4 dv = *(const float4*)&dinv_s[r0];
                union { h16x2 hh[2]; u64 u; } pk;
                if (ct == 0) {
                    pk.hh[0] = __builtin_amdgcn_cvt_pkrtz(c0[q*4+0]*dv.x, c0[q*4+1]*dv.y);
                    pk.hh[1] = __builtin_amdgcn_cvt_pkrtz(c0[q*4+2]*dv.z, c0[q*4+3]*dv.w);
                } else {
                    pk.hh[0] = __builtin_amdgcn_cvt_pkrtz(c1[q*4+0]*dv.x, c1[q*4+1]*dv.y);
                    pk.hh[1] = __builtin_amdgcn_cvt_pkrtz(c1[q*4+2]*dv.z, c1[q*4+3]*dv.w);
                }
                *(u64*)(mat0 + h*256 + SWZ16(h, r0*2)) = pk.u;
            }
        }
    }
    __syncthreads();

    // ---- phase 3: agg1 -> X2[j][h] in mat1 ----
    agg_mm(mat0, mat1, cmask, dinv_s, b1s, lut16, wv, lane);
    __syncthreads();

    // ---- phase 4: build W2T f16 image in mat0 (from W2g, coalesced), then conv2 ----
    {
        #pragma unroll
        for (int rep = 0; rep < 4; ++rep) {
            const int idx = rep*512 + t;         // 2048 tiles: h2 = idx&127, g = idx>>7
            const int h2 = idx & 127, g = idx >> 7;
            f16x8 v;
            #pragma unroll
            for (int s = 0; s < 8; ++s) v[s] = (f16)W2g[(g*8 + s)*128 + h2];   // RTN cvt
            *(f16x8*)(mat0 + h2*256 + SWZ16(h2, g*16)) = v;
        }
    }
    __syncthreads();
    {
        f32x16 c0, c1;
        #pragma unroll
        for (int e = 0; e < 16; ++e) { c0[e] = 0.f; c1[e] = 0.f; }
        const int rb = wv & 3, ch = wv >> 2;
        const int row = rb*32 + lr;              // j
        __builtin_amdgcn_s_setprio(1);
        #pragma unroll
        for (int ks = 0; ks < 8; ++ks) {
            const f16x8 af = *(const f16x8*)(mat1 + row*256 + SWZ16(row, ks*32 + lg*16));
            #pragma unroll
            for (int ct = 0; ct < 2; ++ct) {
                const int h2 = ch*64 + ct*32 + lr;
                const f16x8 bf = *(const f16x8*)(mat0 + h2*256 + SWZ16(h2, ks*32 + lg*16));
                if (ct == 0) c0 = MFMA(af, bf, c0, 0, 0, 0);
                else         c1 = MFMA(af, bf, c1, 0, 0, 0);
            }
        }
        __builtin_amdgcn_s_setprio(0);
        __syncthreads();   // X2/W2T reads done before G2 overwrites mat1
        #pragma unroll
        for (int ct = 0; ct < 2; ++ct) {
            const int h2 = ch*64 + ct*32 + lr;
            #pragma unroll
            for (int q = 0; q < 4; ++q) {
                const int r0 = rb*32 + q*8 + lg*4;   // j quad
                const float4 dv = *(const float4*)&dinv_s[r0];
                union { h16x2 hh[2]; u64 u; } pk;
                if (ct == 0) {
                    pk.hh[0] = __builtin_amdgcn_cvt_pkrtz(c0[q*4+0]*dv.x, c0[q*4+1]*dv.y);
                    pk.hh[1] = __builtin_amdgcn_cvt_pkrtz(c0[q*4+2]*dv.z, c0[q*4+3]*dv.w);
                } else {
                    pk.hh[0] = __builtin_amdgcn_cvt_pkrtz(c1[q*4+0]*dv.x, c1[q*4+1]*dv.y);
                    pk.hh[1] = __builtin_amdgcn_cvt_pkrtz(c1[q*4+2]*dv.z, c1[q*4+3]*dv.w);
                }
                *(u64*)(mat1 + h2*256 + SWZ16(h2, r0*2)) = pk.u;
            }
        }
    }
    __syncthreads();

    // ---- phase 5: agg2 -> X3[j][h2] in mat0 ----
    agg_mm(mat1, mat0, cmask, dinv_s, b2s, lut16, wv, lane);
    __syncthreads();

    // ---- phase 6: head out[j] = X3[j].wo + bout ----
    {
        float s = 0.f;
        #pragma unroll
        for (int u = 0; u < 4; ++u) {
            const f16x8 v = *(const f16x8*)(mat0 + ia*256 + SWZ16(ia, p4*64 + u*16));
            const float4 w0 = *(const float4*)&wos[p4*32 + u*8];
            const float4 w1 = *(const float4*)&wos[p4*32 + u*8 + 4];
            s = fmaf((float)v[0], w0.x, s); s = fmaf((float)v[1], w0.y, s);
            s = fmaf((float)v[2], w0.z, s); s = fmaf((float)v[3], w0.w, s);
            s = fmaf((float)v[4], w1.x, s); s = fmaf((float)v[5], w1.y, s);
            s = fmaf((float)v[6], w1.z, s); s = fmaf((float)v[7], w1.w, s);
        }
        s += __shfl_xor(s, 1, 64);
        s += __shfl_xor(s, 2, 64);
        if (p4 == 0) outg[b*NA + ia] = s + bog[0];
    }
}

extern "C" void kernel_launch(void* const* d_in, const int* in_sizes, int n_in,
                              void* d_out, int out_size, void* d_ws, size_t ws_size,
                              hipStream_t stream) {
    const float* obs = (const float*)d_in[0];
    const float* W1  = (const float*)d_in[1];
    const float* b1  = (const float*)d_in[2];
    const float* W2  = (const float*)d_in[3];
    const float* b2  = (const float*)d_in[4];
    const float* Wo  = (const float*)d_in[5];
    const float* bo  = (const float*)d_in[6];
    float* out = (float*)d_out;
    const int B = in_sizes[0] / (NA * 32);
    hipLaunchKernelGGL(gnn_fused, dim3(B), dim3(512), 0, stream,
                       obs, W1, b1, W2, b2, Wo, bo, out);
}

// Round 10
// 33.123 us; speedup vs baseline: 1.7200x; 1.0176x over previous
//
#include <hip/hip_runtime.h>

#define NA 128   // agents per batch
#define NKN 16   // neighbours

typedef _Float16 f16;
typedef __fp16   h16x2 __attribute__((ext_vector_type(2)));   // cvt_pkrtz result type
typedef _Float16 f16x8 __attribute__((ext_vector_type(8)));
typedef float    f32x16 __attribute__((ext_vector_type(16)));
typedef unsigned long long u64;

#define MFMA __builtin_amdgcn_mfma_f32_32x32x16_f16
// 256B-row f16 matrices: XOR row bits into the 16B-slot index -> 16 slots, 2-way (free)
#define SWZ16(row, byteoff) ((byteoff) ^ (((row)&15)<<4))
// 64B-row f16 matrices (X, W1T): 4 slots
#define SWZ4(row, byteoff)  ((byteoff) ^ (((row)&3)<<4))
// candidate-slot swizzle: u64 slot l of agent ia -> spread 16 agents across banks
#define CSW(ia, l) ((l) ^ (((ia) & 15) << 1))

__device__ __forceinline__ float tanh_fast(float x){
    float e = __expf(2.f * x);
    return 1.f - 2.f * __builtin_amdgcn_rcpf(e + 1.f);
}

__device__ __forceinline__ unsigned int wsel(const uint4 c, int i){ // i compile-time
    return i==0 ? c.x : i==1 ? c.y : i==2 ? c.z : c.w;
}

// OUT[h][j] = sum_i IN[h][i]*M[i][j] (M incl. diagonal); X = tanh(d_j*OUT + bias[h]) stored-T.
__device__ __forceinline__ void agg_mm(const unsigned char* matIn, unsigned char* matOut,
                                       const unsigned int (*cmask)[4], const float* dinv_s,
                                       const float* bias, const u64* lut,
                                       int wv, int lane)
{
    const int lr = lane & 31, lg = lane >> 5;
    const int rb = wv & 3, ch = wv >> 2;
    f32x16 c0, c1;
    #pragma unroll
    for (int e = 0; e < 16; ++e) { c0[e] = 0.f; c1[e] = 0.f; }

    const int j0 = ch*64 + lr, j1 = j0 + 32;
    const uint4 cm0 = *(const uint4*)&cmask[j0][0];
    const uint4 cm1 = *(const uint4*)&cmask[j1][0];
    const int row = rb*32 + lr;   // h

    __builtin_amdgcn_s_setprio(1);
    #pragma unroll
    for (int ks = 0; ks < 8; ++ks) {
        f16x8 af = *(const f16x8*)(matIn + row*256 + SWZ16(row, ks*32 + lg*16));
        const int sh = (ks&1)*16 + lg*8;
        const unsigned int b0 = (wsel(cm0, ks>>1) >> sh) & 0xFFu;
        const unsigned int b1 = (wsel(cm1, ks>>1) >> sh) & 0xFFu;
        union { f16x8 v; u64 u[2]; } B0, B1;
        B0.u[0] = lut[b0 & 15u]; B0.u[1] = lut[b0 >> 4];
        B1.u[0] = lut[b1 & 15u]; B1.u[1] = lut[b1 >> 4];
        c0 = MFMA(af, B0.v, c0, 0, 0, 0);
        c1 = MFMA(af, B1.v, c1, 0, 0, 0);
    }
    __builtin_amdgcn_s_setprio(0);
    #pragma unroll
    for (int ct = 0; ct < 2; ++ct) {
        const int j = ct ? j1 : j0;
        const float dj = dinv_s[j];
        #pragma unroll
        for (int q = 0; q < 4; ++q) {
            const int r0 = rb*32 + q*8 + lg*4;   // h quad
            const float4 bv = *(const float4*)&bias[r0];
            float v0, v1, v2, v3;
            if (ct == 0) {
                v0 = tanh_fast(fmaf(dj, c0[q*4+0], bv.x));
                v1 = tanh_fast(fmaf(dj, c0[q*4+1], bv.y));
                v2 = tanh_fast(fmaf(dj, c0[q*4+2], bv.z));
                v3 = tanh_fast(fmaf(dj, c0[q*4+3], bv.w));
            } else {
                v0 = tanh_fast(fmaf(dj, c1[q*4+0], bv.x));
                v1 = tanh_fast(fmaf(dj, c1[q*4+1], bv.y));
                v2 = tanh_fast(fmaf(dj, c1[q*4+2], bv.z));
                v3 = tanh_fast(fmaf(dj, c1[q*4+3], bv.w));
            }
            union { h16x2 h[2]; u64 u; } pk;
            pk.h[0] = __builtin_amdgcn_cvt_pkrtz(v0, v1);
            pk.h[1] = __builtin_amdgcn_cvt_pkrtz(v2, v3);
            *(u64*)(matOut + j*256 + SWZ16(j, r0*2)) = pk.u;
        }
    }
}

__global__ __launch_bounds__(512, 4) void gnn_fused(
    const float* __restrict__ obs,
    const float* __restrict__ W1g, const float* __restrict__ b1g,
    const float* __restrict__ W2g, const float* __restrict__ b2g,
    const float* __restrict__ Wog, const float* __restrict__ bog,
    float* __restrict__ outg)
{
    __shared__ __align__(16) unsigned char mat0[32768]; // cand -> G1 -> W2T -> head partials
    __shared__ __align__(16) unsigned char mat1[32768]; // Xf16(8K) -> X2 -> G2
    __shared__ __align__(16) unsigned char w1t[8192];   // W1T image (own buffer)
    __shared__ float posx[NA], posy[NA], dinv_s[NA], b1s[NA], b2s[NA], wos[NA];
    __shared__ unsigned int cmask[NA][4];
    __shared__ u64 lut16[16];

    const int t = threadIdx.x;
    const int b = blockIdx.x;
    const int wv = t >> 6, lane = t & 63;
    const int lr = lane & 31, lg = lane >> 5;

    // ---- phase 0: stage obs->Xf16 (+pos), W1T, params, cmask diag, LUT, cand init ----
    {
        const float4* ob = (const float4*)(obs + (size_t)b * NA * 32);
        #pragma unroll
        for (int rep = 0; rep < 2; ++rep) {
            const int idx = rep*512 + t;         // 1024 float4 = [128 i][8 seg]
            const int i = idx >> 3, seg = idx & 7;
            const float4 v = ob[idx];
            if (seg == 0) { posx[i] = v.x; posy[i] = v.y; }
            union { h16x2 h[2]; u64 u; } pk;
            pk.h[0] = __builtin_amdgcn_cvt_pkrtz(v.x, v.y);
            pk.h[1] = __builtin_amdgcn_cvt_pkrtz(v.z, v.w);
            *(u64*)(mat1 + i*64 + SWZ4(i, seg*8)) = pk.u;
        }
        {   // W1T tile per thread: h = t&127, g = t>>7 (coalesced over h)
            const int h = t & 127, g = t >> 7;
            f16x8 v;
            #pragma unroll
            for (int s = 0; s < 8; ++s) v[s] = (f16)W1g[(g*8 + s)*128 + h];   // RTN cvt
            *(f16x8*)(w1t + h*64 + SWZ4(h, g*16)) = v;
        }
        u64* cand = (u64*)mat0;                  // 4096 u64 slots = 128 agents x 32
        #pragma unroll
        for (int s = 0; s < 8; ++s) cand[t*8 + s] = ~0ull;
        if (t < NA) { b1s[t] = b1g[t]; b2s[t] = b2g[t]; wos[t] = Wog[t]; }
        { const int j = t >> 2, w = t & 3; cmask[j][w] = (w == (j>>5)) ? (1u << (j&31)) : 0u; }
        if (t < 16) {
            u64 e = 0ull;
            #pragma unroll
            for (int s = 0; s < 4; ++s)
                if ((t >> s) & 1) e |= 0x3C00ull << (16*s);   // f16 1.0
            lut16[t] = e;
        }
    }
    __syncthreads();

    // ---- phase 1: exact kNN via pivot-bisection + prefix compaction (no atomics) ----
    const int ia = t >> 2, p4 = t & 3;
    int mtot;
    {
        u64* cand = (u64*)mat0;
        // 1a: distance bit-keys (bit-exact vs ref: rn mul/add, rn sqrt; monotone u32)
        unsigned int kd[32];
        const float xi = posx[ia], yi = posy[ia];
        #pragma unroll
        for (int jj = 0; jj < 32; ++jj) {
            const int j = p4*32 + jj;
            const float dx = __fsub_rn(xi, posx[j]);
            const float dy = __fsub_rn(yi, posy[j]);
            const float d  = __fsqrt_rn(__fadd_rn(__fmul_rn(dx,dx), __fmul_rn(dy,dy)));
            kd[jj] = __float_as_uint(d);         // self: exactly 0
        }
        // 1b: bisect pivot P until 17 <= count(kd < P) <= 32 (wide window: ~3-6 iters)
        unsigned int lo = 0u, hi = 0xFF000000u, P = 0u;
        bool done = false;
        #pragma unroll 1
        for (int it = 0; it < 34; ++it) {
            const unsigned int mid = (lo + hi) >> 1;
            int cl = 0;
            #pragma unroll
            for (int jj = 0; jj < 32; ++jj) cl += (kd[jj] < mid) ? 1 : 0;
            cl += __shfl_xor(cl, 1, 64);
            cl += __shfl_xor(cl, 2, 64);
            if (!done) {
                if (cl >= 17 && cl <= 32) { P = mid; done = true; }
                else if (cl < 17) lo = mid;
                else hi = mid;
                if (hi - lo <= 1u && !done) { P = hi; done = true; }
            }
            if (__all(done ? 1 : 0)) break;
        }
        if (!done) P = hi;
        // 1c: deterministic compaction: per-lane bitmask -> 4-lane exclusive prefix
        unsigned int maskp = 0u;
        #pragma unroll
        for (int jj = 0; jj < 32; ++jj) maskp |= (kd[jj] < P) ? (1u << jj) : 0u;
        const int cnt = __popc(maskp);
        const int base = lane & ~3;
        const int c0n = __shfl(cnt, base + 0, 64);
        const int c1n = __shfl(cnt, base + 1, 64);
        const int c2n = __shfl(cnt, base + 2, 64);
        const int c3n = __shfl(cnt, base + 3, 64);
        mtot = c0n + c1n + c2n + c3n;
        int slot = (p4 > 0 ? c0n : 0) + (p4 > 1 ? c1n : 0) + (p4 > 2 ? c2n : 0);
        #pragma unroll
        for (int jj = 0; jj < 32; ++jj) {
            if ((maskp >> jj) & 1u) {
                if (slot < 32)
                    cand[ia*32 + CSW(ia, slot)] = ((u64)kd[jj] << 32) | (unsigned)(p4*32 + jj);
                ++slot;
            }
        }
    }
    __syncthreads();
    {
        const u64* cand = (const u64*)mat0;
        // 1d: rank among candidates (exact (dist,idx) lexicographic order).
        // rank r in [1,16] => neighbor (rank 0 = the dropped first top_k entry, exactly
        // matching top_k(-d,17)[1:] incl. duplicate-position degeneracy).
        // STATIC register indexing only (rule #20).
        u64 ck8[8];
        int rk[8];
        #pragma unroll
        for (int q = 0; q < 8; ++q) {
            ck8[q] = cand[ia*32 + CSW(ia, 8*p4 + q)];
            rk[q] = 0;
        }
        #pragma unroll
        for (int e = 0; e < 32; ++e) {
            const u64 ke = cand[ia*32 + CSW(ia, e)];
            #pragma unroll
            for (int q = 0; q < 8; ++q) rk[q] += (ke < ck8[q]) ? 1 : 0;
        }
        const int m = min(mtot, 32);
        #pragma unroll
        for (int q = 0; q < 8; ++q) {
            const int c = 8*p4 + q;
            if (c < m && rk[q] >= 1 && rk[q] < 17) {
                const int n = (int)(ck8[q] & 127u);
                atomicOr(&cmask[n][ia >> 5], 1u << (ia & 31));
            }
        }
    }
    __syncthreads();
    // ---- degrees (needs complete cmask; barrier before conv1 epilogue reads dinv) ----
    if (t < NA)
        dinv_s[t] = rsqrtf((float)(__popc(cmask[t][0]) + __popc(cmask[t][1]) +
                                   __popc(cmask[t][2]) + __popc(cmask[t][3])));
    __syncthreads();

    // ---- phase 2: conv1  G1[h][i] = d_i*(X@W1)[i][h]; no mid-barrier (W1T separate) ----
    {
        f32x16 c0, c1;
        #pragma unroll
        for (int e = 0; e < 16; ++e) { c0[e] = 0.f; c1[e] = 0.f; }
        const int rb = wv & 3, ch = wv >> 2;
        const int row = rb*32 + lr;              // node i
        #pragma unroll
        for (int ks = 0; ks < 2; ++ks) {
            const f16x8 af = *(const f16x8*)(mat1 + row*64 + SWZ4(row, ks*32 + lg*16));
            #pragma unroll
            for (int ct = 0; ct < 2; ++ct) {
                const int h = ch*64 + ct*32 + lr;
                const f16x8 bf = *(const f16x8*)(w1t + h*64 + SWZ4(h, ks*32 + lg*16));
                if (ct == 0) c0 = MFMA(af, bf, c0, 0, 0, 0);
                else         c1 = MFMA(af, bf, c1, 0, 0, 0);
            }
        }
        // epilogue writes G1 into mat0 (cand dead since rank barrier) -- no barrier needed
        #pragma unroll
        for (int ct = 0; ct < 2; ++ct) {
            const int h = ch*64 + ct*32 + lr;
            #pragma unroll
            for (int q = 0; q < 4; ++q) {
                const int r0 = rb*32 + q*8 + lg*4;   // node quad
                const float4 dv = *(const float4*)&dinv_s[r0];
                union { h16x2 hh[2]; u64 u; } pk;
                if (ct == 0) {
                    pk.hh[0] = __builtin_amdgcn_cvt_pkrtz(c0[q*4+0]*dv.x, c0[q*4+1]*dv.y);
                    pk.hh[1] = __builtin_amdgcn_cvt_pkrtz(c0[q*4+2]*dv.z, c0[q*4+3]*dv.w);
                } else {
                    pk.hh[0] = __builtin_amdgcn_cvt_pkrtz(c1[q*4+0]*dv.x, c1[q*4+1]*dv.y);
                    pk.hh[1] = __builtin_amdgcn_cvt_pkrtz(c1[q*4+2]*dv.z, c1[q*4+3]*dv.w);
                }
                *(u64*)(mat0 + h*256 + SWZ16(h, r0*2)) = pk.u;
            }
        }
    }
    // ---- T14: issue W2 global loads now; consumed after agg1 (latency hides under MFMA) ----
    float w2r[32];
    #pragma unroll
    for (int r = 0; r < 4; ++r) {
        const int idx = r*512 + t, h2 = idx & 127, g = idx >> 7;
        #pragma unroll
        for (int s = 0; s < 8; ++s) w2r[r*8 + s] = W2g[(g*8 + s)*128 + h2];
    }
    __syncthreads();

    // ---- phase 3: agg1 -> X2[j][h] in mat1 ----
    agg_mm(mat0, mat1, cmask, dinv_s, b1s, lut16, wv, lane);
    __syncthreads();

    // ---- phase 4: store W2T f16 image to mat0 (RTN cvt from regs), then conv2 ----
    {
        #pragma unroll
        for (int r = 0; r < 4; ++r) {
            const int idx = r*512 + t, h2 = idx & 127, g = idx >> 7;
            f16x8 v;
            #pragma unroll
            for (int s = 0; s < 8; ++s) v[s] = (f16)w2r[r*8 + s];   // RTN cvt
            *(f16x8*)(mat0 + h2*256 + SWZ16(h2, g*16)) = v;
        }
    }
    __syncthreads();
    {
        f32x16 c0, c1;
        #pragma unroll
        for (int e = 0; e < 16; ++e) { c0[e] = 0.f; c1[e] = 0.f; }
        const int rb = wv & 3, ch = wv >> 2;
        const int row = rb*32 + lr;              // j
        __builtin_amdgcn_s_setprio(1);
        #pragma unroll
        for (int ks = 0; ks < 8; ++ks) {
            const f16x8 af = *(const f16x8*)(mat1 + row*256 + SWZ16(row, ks*32 + lg*16));
            #pragma unroll
            for (int ct = 0; ct < 2; ++ct) {
                const int h2 = ch*64 + ct*32 + lr;
                const f16x8 bf = *(const f16x8*)(mat0 + h2*256 + SWZ16(h2, ks*32 + lg*16));
                if (ct == 0) c0 = MFMA(af, bf, c0, 0, 0, 0);
                else         c1 = MFMA(af, bf, c1, 0, 0, 0);
            }
        }
        __builtin_amdgcn_s_setprio(0);
        __syncthreads();   // X2/W2T reads done before G2 overwrites mat1
        #pragma unroll
        for (int ct = 0; ct < 2; ++ct) {
            const int h2 = ch*64 + ct*32 + lr;
            #pragma unroll
            for (int q = 0; q < 4; ++q) {
                const int r0 = rb*32 + q*8 + lg*4;   // j quad
                const float4 dv = *(const float4*)&dinv_s[r0];
                union { h16x2 hh[2]; u64 u; } pk;
                if (ct == 0) {
                    pk.hh[0] = __builtin_amdgcn_cvt_pkrtz(c0[q*4+0]*dv.x, c0[q*4+1]*dv.y);
                    pk.hh[1] = __builtin_amdgcn_cvt_pkrtz(c0[q*4+2]*dv.z, c0[q*4+3]*dv.w);
                } else {
                    pk.hh[0] = __builtin_amdgcn_cvt_pkrtz(c1[q*4+0]*dv.x, c1[q*4+1]*dv.y);
                    pk.hh[1] = __builtin_amdgcn_cvt_pkrtz(c1[q*4+2]*dv.z, c1[q*4+3]*dv.w);
                }
                *(u64*)(mat1 + h2*256 + SWZ16(h2, r0*2)) = pk.u;
            }
        }
    }
    __syncthreads();

    // ---- phase 5: agg2 + FUSED head: partial dot with wo in-register, no X3 store ----
    {
        const int rb = wv & 3, ch = wv >> 2;
        f32x16 c0, c1;
        #pragma unroll
        for (int e = 0; e < 16; ++e) { c0[e] = 0.f; c1[e] = 0.f; }
        const int j0 = ch*64 + lr, j1 = j0 + 32;
        const uint4 cm0 = *(const uint4*)&cmask[j0][0];
        const uint4 cm1 = *(const uint4*)&cmask[j1][0];
        const int row = rb*32 + lr;   // h2
        __builtin_amdgcn_s_setprio(1);
        #pragma unroll
        for (int ks = 0; ks < 8; ++ks) {
            f16x8 af = *(const f16x8*)(mat1 + row*256 + SWZ16(row, ks*32 + lg*16));
            const int sh = (ks&1)*16 + lg*8;
            const unsigned int b0m = (wsel(cm0, ks>>1) >> sh) & 0xFFu;
            const unsigned int b1m = (wsel(cm1, ks>>1) >> sh) & 0xFFu;
            union { f16x8 v; u64 u[2]; } B0, B1;
            B0.u[0] = lut16[b0m & 15u]; B0.u[1] = lut16[b0m >> 4];
            B1.u[0] = lut16[b1m & 15u]; B1.u[1] = lut16[b1m >> 4];
            c0 = MFMA(af, B0.v, c0, 0, 0, 0);
            c1 = MFMA(af, B1.v, c1, 0, 0, 0);
        }
        __builtin_amdgcn_s_setprio(0);
        float* acc = (float*)mat0;   // [128 j][8 (rb*2+lg)] partials; W2T dead after conv2-end
        #pragma unroll
        for (int ct = 0; ct < 2; ++ct) {
            const int j = ct ? j1 : j0;
            const float dj = dinv_s[j];
            float part = 0.f;
            #pragma unroll
            for (int q = 0; q < 4; ++q) {
                const int r0 = rb*32 + q*8 + lg*4;   // h2 quad
                const float4 bv = *(const float4*)&b2s[r0];
                const float4 wq = *(const float4*)&wos[r0];
                float v0, v1, v2, v3;
                if (ct == 0) {
                    v0 = tanh_fast(fmaf(dj, c0[q*4+0], bv.x));
                    v1 = tanh_fast(fmaf(dj, c0[q*4+1], bv.y));
                    v2 = tanh_fast(fmaf(dj, c0[q*4+2], bv.z));
                    v3 = tanh_fast(fmaf(dj, c0[q*4+3], bv.w));
                } else {
                    v0 = tanh_fast(fmaf(dj, c1[q*4+0], bv.x));
                    v1 = tanh_fast(fmaf(dj, c1[q*4+1], bv.y));
                    v2 = tanh_fast(fmaf(dj, c1[q*4+2], bv.z));
                    v3 = tanh_fast(fmaf(dj, c1[q*4+3], bv.w));
                }
                part = fmaf(v0, wq.x, part); part = fmaf(v1, wq.y, part);
                part = fmaf(v2, wq.z, part); part = fmaf(v3, wq.w, part);
            }
            acc[j*8 + rb*2 + lg] = part;
        }
    }
    __syncthreads();
    if (t < NA) {
        const float* a = (const float*)mat0 + t*8;
        const float s = ((a[0] + a[1]) + (a[2] + a[3])) + ((a[4] + a[5]) + (a[6] + a[7]));
        outg[b*NA + t] = s + bog[0];
    }
}

extern "C" void kernel_launch(void* const* d_in, const int* in_sizes, int n_in,
                              void* d_out, int out_size, void* d_ws, size_t ws_size,
                              hipStream_t stream) {
    const float* obs = (const float*)d_in[0];
    const float* W1  = (const float*)d_in[1];
    const float* b1  = (const float*)d_in[2];
    const float* W2  = (const float*)d_in[3];
    const float* b2  = (const float*)d_in[4];
    const float* Wo  = (const float*)d_in[5];
    const float* bo  = (const float*)d_in[6];
    float* out = (float*)d_out;
    const int B = in_sizes[0] / (NA * 32);
    hipLaunchKernelGGL(gnn_fused, dim3(B), dim3(512), 0, stream,
                       obs, W1, b1, W2, b2, Wo, bo, out);
}

// Round 11
// 32.052 us; speedup vs baseline: 1.7775x; 1.0334x over previous
//
#include <hip/hip_runtime.h>

#define NA 128   // agents per batch
#define NKN 16   // neighbours
#define NCAND 24 // candidate cap (bisect window [17,24])

typedef _Float16 f16;
typedef __fp16   h16x2 __attribute__((ext_vector_type(2)));   // cvt_pkrtz result type
typedef _Float16 f16x8 __attribute__((ext_vector_type(8)));
typedef float    f32x16 __attribute__((ext_vector_type(16)));
typedef unsigned long long u64;

#define MFMA __builtin_amdgcn_mfma_f32_32x32x16_f16
// 256B-row f16 matrices: XOR row bits into the 16B-slot index -> 16 slots, 2-way (free)
#define SWZ16(row, byteoff) ((byteoff) ^ (((row)&15)<<4))
// 64B-row f16 matrices (X, W1T): 4 slots
#define SWZ4(row, byteoff)  ((byteoff) ^ (((row)&3)<<4))
// candidate-slot swizzle: u64 slot l of agent ia -> spread 16 agents across banks
#define CSW(ia, l) ((l) ^ (((ia) & 15) << 1))

__device__ __forceinline__ float tanh_fast(float x){
    float e = __expf(2.f * x);
    return 1.f - 2.f * __builtin_amdgcn_rcpf(e + 1.f);
}

__device__ __forceinline__ unsigned int wsel(const uint4 c, int i){ // i compile-time
    return i==0 ? c.x : i==1 ? c.y : i==2 ? c.z : c.w;
}

// OUT[h][j] = sum_i IN[h][i]*M[i][j] (M incl. diagonal); X = tanh(d_j*OUT + bias[h]) stored-T.
__device__ __forceinline__ void agg_mm(const unsigned char* matIn, unsigned char* matOut,
                                       const unsigned int (*cmask)[4], const float* dinv_s,
                                       const float* bias, const u64* lut,
                                       int wv, int lane)
{
    const int lr = lane & 31, lg = lane >> 5;
    const int rb = wv & 3, ch = wv >> 2;
    f32x16 c0, c1;
    #pragma unroll
    for (int e = 0; e < 16; ++e) { c0[e] = 0.f; c1[e] = 0.f; }

    const int j0 = ch*64 + lr, j1 = j0 + 32;
    const uint4 cm0 = *(const uint4*)&cmask[j0][0];
    const uint4 cm1 = *(const uint4*)&cmask[j1][0];
    const int row = rb*32 + lr;   // h

    __builtin_amdgcn_s_setprio(1);
    #pragma unroll
    for (int ks = 0; ks < 8; ++ks) {
        f16x8 af = *(const f16x8*)(matIn + row*256 + SWZ16(row, ks*32 + lg*16));
        const int sh = (ks&1)*16 + lg*8;
        const unsigned int b0 = (wsel(cm0, ks>>1) >> sh) & 0xFFu;
        const unsigned int b1 = (wsel(cm1, ks>>1) >> sh) & 0xFFu;
        union { f16x8 v; u64 u[2]; } B0, B1;
        B0.u[0] = lut[b0 & 15u]; B0.u[1] = lut[b0 >> 4];
        B1.u[0] = lut[b1 & 15u]; B1.u[1] = lut[b1 >> 4];
        c0 = MFMA(af, B0.v, c0, 0, 0, 0);
        c1 = MFMA(af, B1.v, c1, 0, 0, 0);
    }
    __builtin_amdgcn_s_setprio(0);
    #pragma unroll
    for (int ct = 0; ct < 2; ++ct) {
        const int j = ct ? j1 : j0;
        const float dj = dinv_s[j];
        #pragma unroll
        for (int q = 0; q < 4; ++q) {
            const int r0 = rb*32 + q*8 + lg*4;   // h quad
            const float4 bv = *(const float4*)&bias[r0];
            float v0, v1, v2, v3;
            if (ct == 0) {
                v0 = tanh_fast(fmaf(dj, c0[q*4+0], bv.x));
                v1 = tanh_fast(fmaf(dj, c0[q*4+1], bv.y));
                v2 = tanh_fast(fmaf(dj, c0[q*4+2], bv.z));
                v3 = tanh_fast(fmaf(dj, c0[q*4+3], bv.w));
            } else {
                v0 = tanh_fast(fmaf(dj, c1[q*4+0], bv.x));
                v1 = tanh_fast(fmaf(dj, c1[q*4+1], bv.y));
                v2 = tanh_fast(fmaf(dj, c1[q*4+2], bv.z));
                v3 = tanh_fast(fmaf(dj, c1[q*4+3], bv.w));
            }
            union { h16x2 h[2]; u64 u; } pk;
            pk.h[0] = __builtin_amdgcn_cvt_pkrtz(v0, v1);
            pk.h[1] = __builtin_amdgcn_cvt_pkrtz(v2, v3);
            *(u64*)(matOut + j*256 + SWZ16(j, r0*2)) = pk.u;
        }
    }
}

__global__ __launch_bounds__(512, 4) void gnn_fused(
    const float* __restrict__ obs,
    const float* __restrict__ W1g, const float* __restrict__ b1g,
    const float* __restrict__ W2g, const float* __restrict__ b2g,
    const float* __restrict__ Wog, const float* __restrict__ bog,
    float* __restrict__ outg)
{
    __shared__ __align__(16) unsigned char mat0[32768]; // cand -> G1 -> W2T -> head partials
    __shared__ __align__(16) unsigned char mat1[32768]; // Xf16(8K) -> X2 -> G2
    __shared__ __align__(16) unsigned char w1t[8192];   // W1T image (own buffer)
    __shared__ float posx[NA], posy[NA], dinv_s[NA], b1s[NA], b2s[NA], wos[NA];
    __shared__ unsigned int cmask[NA][4];
    __shared__ u64 lut16[16];

    const int t = threadIdx.x;
    const int b = blockIdx.x;
    const int wv = t >> 6, lane = t & 63;
    const int lr = lane & 31, lg = lane >> 5;

    // ---- phase 0: stage obs->Xf16 (+pos), W1T, params, cmask diag, LUT, cand init ----
    {
        const float4* ob = (const float4*)(obs + (size_t)b * NA * 32);
        #pragma unroll
        for (int rep = 0; rep < 2; ++rep) {
            const int idx = rep*512 + t;         // 1024 float4 = [128 i][8 seg]
            const int i = idx >> 3, seg = idx & 7;
            const float4 v = ob[idx];
            if (seg == 0) { posx[i] = v.x; posy[i] = v.y; }
            union { h16x2 h[2]; u64 u; } pk;
            pk.h[0] = __builtin_amdgcn_cvt_pkrtz(v.x, v.y);
            pk.h[1] = __builtin_amdgcn_cvt_pkrtz(v.z, v.w);
            *(u64*)(mat1 + i*64 + SWZ4(i, seg*8)) = pk.u;
        }
        {   // W1T tile per thread: h = t&127, g = t>>7 (coalesced over h)
            const int h = t & 127, g = t >> 7;
            f16x8 v;
            #pragma unroll
            for (int s = 0; s < 8; ++s) v[s] = (f16)W1g[(g*8 + s)*128 + h];   // RTN cvt
            *(f16x8*)(w1t + h*64 + SWZ4(h, g*16)) = v;
        }
        u64* cand = (u64*)mat0;                  // 4096 u64 slots = 128 agents x 32
        #pragma unroll
        for (int s = 0; s < 8; ++s) cand[t*8 + s] = ~0ull;
        if (t < NA) { b1s[t] = b1g[t]; b2s[t] = b2g[t]; wos[t] = Wog[t]; }
        { const int j = t >> 2, w = t & 3; cmask[j][w] = (w == (j>>5)) ? (1u << (j&31)) : 0u; }
        if (t < 16) {
            u64 e = 0ull;
            #pragma unroll
            for (int s = 0; s < 4; ++s)
                if ((t >> s) & 1) e |= 0x3C00ull << (16*s);   // f16 1.0
            lut16[t] = e;
        }
    }
    __syncthreads();

    // ---- phase 1: exact kNN via pivot-bisection (window [17,24]) + prefix compaction ----
    const int ia = t >> 2, p4 = t & 3;
    int mtot;
    {
        u64* cand = (u64*)mat0;
        // 1a: distance bit-keys (bit-exact vs ref: rn mul/add, rn sqrt; monotone u32)
        unsigned int kd[32];
        const float xi = posx[ia], yi = posy[ia];
        #pragma unroll
        for (int jj = 0; jj < 32; ++jj) {
            const int j = p4*32 + jj;
            const float dx = __fsub_rn(xi, posx[j]);
            const float dy = __fsub_rn(yi, posy[j]);
            const float d  = __fsqrt_rn(__fadd_rn(__fmul_rn(dx,dx), __fmul_rn(dy,dy)));
            kd[jj] = __float_as_uint(d);         // self: exactly 0
        }
        // 1b: bisect pivot P until 17 <= count(kd < P) <= NCAND (narrow window)
        unsigned int lo = 0u, hi = 0xFF000000u, P = 0u;
        bool done = false;
        #pragma unroll 1
        for (int it = 0; it < 34; ++it) {
            const unsigned int mid = (lo + hi) >> 1;
            int cl = 0;
            #pragma unroll
            for (int jj = 0; jj < 32; ++jj) cl += (kd[jj] < mid) ? 1 : 0;
            cl += __shfl_xor(cl, 1, 64);
            cl += __shfl_xor(cl, 2, 64);
            if (!done) {
                if (cl >= 17 && cl <= NCAND) { P = mid; done = true; }
                else if (cl < 17) lo = mid;
                else hi = mid;
                if (hi - lo <= 1u && !done) { P = hi; done = true; }
            }
            if (__all(done ? 1 : 0)) break;
        }
        if (!done) P = hi;
        // 1c: compaction via parallel popc-prefix (no serial slot chain, no atomics)
        unsigned int maskp = 0u;
        #pragma unroll
        for (int jj = 0; jj < 32; ++jj) maskp |= (kd[jj] < P) ? (1u << jj) : 0u;
        const int cnt = __popc(maskp);
        const int base = lane & ~3;
        const int c0n = __shfl(cnt, base + 0, 64);
        const int c1n = __shfl(cnt, base + 1, 64);
        const int c2n = __shfl(cnt, base + 2, 64);
        const int c3n = __shfl(cnt, base + 3, 64);
        mtot = c0n + c1n + c2n + c3n;
        const int pbase = (p4 > 0 ? c0n : 0) + (p4 > 1 ? c1n : 0) + (p4 > 2 ? c2n : 0);
        #pragma unroll
        for (int jj = 0; jj < 32; ++jj) {
            if ((maskp >> jj) & 1u) {
                const int slot = pbase + __popc(maskp & ((1u << jj) - 1u));
                if (slot < NCAND)
                    cand[ia*32 + CSW(ia, slot)] = ((u64)kd[jj] << 32) | (unsigned)(p4*32 + jj);
            }
        }
    }
    __syncthreads();
    {
        const u64* cand = (const u64*)mat0;
        // 1d: rank among <=24 candidates (exact (dist,idx) lexicographic order).
        // rank r in [1,16] => neighbor (rank 0 = the dropped first top_k entry, exactly
        // matching top_k(-d,17)[1:] incl. duplicate-position degeneracy).
        // STATIC register indexing only (rule #20): lane owns 6 candidates.
        u64 ck6[6];
        int rk[6];
        #pragma unroll
        for (int q = 0; q < 6; ++q) {
            ck6[q] = cand[ia*32 + CSW(ia, 6*p4 + q)];
            rk[q] = 0;
        }
        #pragma unroll
        for (int e = 0; e < NCAND; ++e) {
            const u64 ke = cand[ia*32 + CSW(ia, e)];
            #pragma unroll
            for (int q = 0; q < 6; ++q) rk[q] += (ke < ck6[q]) ? 1 : 0;
        }
        const int m = min(mtot, NCAND);
        #pragma unroll
        for (int q = 0; q < 6; ++q) {
            const int c = 6*p4 + q;
            if (c < m && rk[q] >= 1 && rk[q] < 17) {
                const int n = (int)(ck6[q] & 127u);
                atomicOr(&cmask[n][ia >> 5], 1u << (ia & 31));
            }
        }
    }
    __syncthreads();
    // ---- degrees (needs complete cmask; barrier before conv1 epilogue reads dinv) ----
    if (t < NA)
        dinv_s[t] = rsqrtf((float)(__popc(cmask[t][0]) + __popc(cmask[t][1]) +
                                   __popc(cmask[t][2]) + __popc(cmask[t][3])));
    __syncthreads();

    // ---- phase 2: conv1  G1[h][i] = d_i*(X@W1)[i][h]; no mid-barrier (W1T separate) ----
    {
        f32x16 c0, c1;
        #pragma unroll
        for (int e = 0; e < 16; ++e) { c0[e] = 0.f; c1[e] = 0.f; }
        const int rb = wv & 3, ch = wv >> 2;
        const int row = rb*32 + lr;              // node i
        #pragma unroll
        for (int ks = 0; ks < 2; ++ks) {
            const f16x8 af = *(const f16x8*)(mat1 + row*64 + SWZ4(row, ks*32 + lg*16));
            #pragma unroll
            for (int ct = 0; ct < 2; ++ct) {
                const int h = ch*64 + ct*32 + lr;
                const f16x8 bf = *(const f16x8*)(w1t + h*64 + SWZ4(h, ks*32 + lg*16));
                if (ct == 0) c0 = MFMA(af, bf, c0, 0, 0, 0);
                else         c1 = MFMA(af, bf, c1, 0, 0, 0);
            }
        }
        // epilogue writes G1 into mat0 (cand dead since rank barrier) -- no barrier needed
        #pragma unroll
        for (int ct = 0; ct < 2; ++ct) {
            const int h = ch*64 + ct*32 + lr;
            #pragma unroll
            for (int q = 0; q < 4; ++q) {
                const int r0 = rb*32 + q*8 + lg*4;   // node quad
                const float4 dv = *(const float4*)&dinv_s[r0];
                union { h16x2 hh[2]; u64 u; } pk;
                if (ct == 0) {
                    pk.hh[0] = __builtin_amdgcn_cvt_pkrtz(c0[q*4+0]*dv.x, c0[q*4+1]*dv.y);
                    pk.hh[1] = __builtin_amdgcn_cvt_pkrtz(c0[q*4+2]*dv.z, c0[q*4+3]*dv.w);
                } else {
                    pk.hh[0] = __builtin_amdgcn_cvt_pkrtz(c1[q*4+0]*dv.x, c1[q*4+1]*dv.y);
                    pk.hh[1] = __builtin_amdgcn_cvt_pkrtz(c1[q*4+2]*dv.z, c1[q*4+3]*dv.w);
                }
                *(u64*)(mat0 + h*256 + SWZ16(h, r0*2)) = pk.u;
            }
        }
    }
    // ---- T14: issue W2 global loads now; consumed after agg1 (latency hides under MFMA) ----
    float w2r[32];
    #pragma unroll
    for (int r = 0; r < 4; ++r) {
        const int idx = r*512 + t, h2 = idx & 127, g = idx >> 7;
        #pragma unroll
        for (int s = 0; s < 8; ++s) w2r[r*8 + s] = W2g[(g*8 + s)*128 + h2];
    }
    __syncthreads();

    // ---- phase 3: agg1 -> X2[j][h] in mat1 ----
    agg_mm(mat0, mat1, cmask, dinv_s, b1s, lut16, wv, lane);
    __syncthreads();

    // ---- phase 4: store W2T f16 image to mat0 (RTN cvt from regs), then conv2 ----
    {
        #pragma unroll
        for (int r = 0; r < 4; ++r) {
            const int idx = r*512 + t, h2 = idx & 127, g = idx >> 7;
            f16x8 v;
            #pragma unroll
            for (int s = 0; s < 8; ++s) v[s] = (f16)w2r[r*8 + s];   // RTN cvt
            *(f16x8*)(mat0 + h2*256 + SWZ16(h2, g*16)) = v;
        }
    }
    __syncthreads();
    {
        f32x16 c0, c1;
        #pragma unroll
        for (int e = 0; e < 16; ++e) { c0[e] = 0.f; c1[e] = 0.f; }
        const int rb = wv & 3, ch = wv >> 2;
        const int row = rb*32 + lr;              // j
        __builtin_amdgcn_s_setprio(1);
        #pragma unroll
        for (int ks = 0; ks < 8; ++ks) {
            const f16x8 af = *(const f16x8*)(mat1 + row*256 + SWZ16(row, ks*32 + lg*16));
            #pragma unroll
            for (int ct = 0; ct < 2; ++ct) {
                const int h2 = ch*64 + ct*32 + lr;
                const f16x8 bf = *(const f16x8*)(mat0 + h2*256 + SWZ16(h2, ks*32 + lg*16));
                if (ct == 0) c0 = MFMA(af, bf, c0, 0, 0, 0);
                else         c1 = MFMA(af, bf, c1, 0, 0, 0);
            }
        }
        __builtin_amdgcn_s_setprio(0);
        __syncthreads();   // X2/W2T reads done before G2 overwrites mat1
        #pragma unroll
        for (int ct = 0; ct < 2; ++ct) {
            const int h2 = ch*64 + ct*32 + lr;
            #pragma unroll
            for (int q = 0; q < 4; ++q) {
                const int r0 = rb*32 + q*8 + lg*4;   // j quad
                const float4 dv = *(const float4*)&dinv_s[r0];
                union { h16x2 hh[2]; u64 u; } pk;
                if (ct == 0) {
                    pk.hh[0] = __builtin_amdgcn_cvt_pkrtz(c0[q*4+0]*dv.x, c0[q*4+1]*dv.y);
                    pk.hh[1] = __builtin_amdgcn_cvt_pkrtz(c0[q*4+2]*dv.z, c0[q*4+3]*dv.w);
                } else {
                    pk.hh[0] = __builtin_amdgcn_cvt_pkrtz(c1[q*4+0]*dv.x, c1[q*4+1]*dv.y);
                    pk.hh[1] = __builtin_amdgcn_cvt_pkrtz(c1[q*4+2]*dv.z, c1[q*4+3]*dv.w);
                }
                *(u64*)(mat1 + h2*256 + SWZ16(h2, r0*2)) = pk.u;
            }
        }
    }
    __syncthreads();

    // ---- phase 5: agg2 + FUSED head: partial dot with wo in-register, no X3 store ----
    {
        const int rb = wv & 3, ch = wv >> 2;
        f32x16 c0, c1;
        #pragma unroll
        for (int e = 0; e < 16; ++e) { c0[e] = 0.f; c1[e] = 0.f; }
        const int j0 = ch*64 + lr, j1 = j0 + 32;
        const uint4 cm0 = *(const uint4*)&cmask[j0][0];
        const uint4 cm1 = *(const uint4*)&cmask[j1][0];
        const int row = rb*32 + lr;   // h2
        __builtin_amdgcn_s_setprio(1);
        #pragma unroll
        for (int ks = 0; ks < 8; ++ks) {
            f16x8 af = *(const f16x8*)(mat1 + row*256 + SWZ16(row, ks*32 + lg*16));
            const int sh = (ks&1)*16 + lg*8;
            const unsigned int b0m = (wsel(cm0, ks>>1) >> sh) & 0xFFu;
            const unsigned int b1m = (wsel(cm1, ks>>1) >> sh) & 0xFFu;
            union { f16x8 v; u64 u[2]; } B0, B1;
            B0.u[0] = lut16[b0m & 15u]; B0.u[1] = lut16[b0m >> 4];
            B1.u[0] = lut16[b1m & 15u]; B1.u[1] = lut16[b1m >> 4];
            c0 = MFMA(af, B0.v, c0, 0, 0, 0);
            c1 = MFMA(af, B1.v, c1, 0, 0, 0);
        }
        __builtin_amdgcn_s_setprio(0);
        float* acc = (float*)mat0;   // [128 j][8 (rb*2+lg)] partials; W2T dead after conv2-end
        #pragma unroll
        for (int ct = 0; ct < 2; ++ct) {
            const int j = ct ? j1 : j0;
            const float dj = dinv_s[j];
            float part = 0.f;
            #pragma unroll
            for (int q = 0; q < 4; ++q) {
                const int r0 = rb*32 + q*8 + lg*4;   // h2 quad
                const float4 bv = *(const float4*)&b2s[r0];
                const float4 wq = *(const float4*)&wos[r0];
                float v0, v1, v2, v3;
                if (ct == 0) {
                    v0 = tanh_fast(fmaf(dj, c0[q*4+0], bv.x));
                    v1 = tanh_fast(fmaf(dj, c0[q*4+1], bv.y));
                    v2 = tanh_fast(fmaf(dj, c0[q*4+2], bv.z));
                    v3 = tanh_fast(fmaf(dj, c0[q*4+3], bv.w));
                } else {
                    v0 = tanh_fast(fmaf(dj, c1[q*4+0], bv.x));
                    v1 = tanh_fast(fmaf(dj, c1[q*4+1], bv.y));
                    v2 = tanh_fast(fmaf(dj, c1[q*4+2], bv.z));
                    v3 = tanh_fast(fmaf(dj, c1[q*4+3], bv.w));
                }
                part = fmaf(v0, wq.x, part); part = fmaf(v1, wq.y, part);
                part = fmaf(v2, wq.z, part); part = fmaf(v3, wq.w, part);
            }
            acc[j*8 + rb*2 + lg] = part;
        }
    }
    __syncthreads();
    if (t < NA) {
        const float* a = (const float*)mat0 + t*8;
        const float s = ((a[0] + a[1]) + (a[2] + a[3])) + ((a[4] + a[5]) + (a[6] + a[7]));
        outg[b*NA + t] = s + bog[0];
    }
}

extern "C" void kernel_launch(void* const* d_in, const int* in_sizes, int n_in,
                              void* d_out, int out_size, void* d_ws, size_t ws_size,
                              hipStream_t stream) {
    const float* obs = (const float*)d_in[0];
    const float* W1  = (const float*)d_in[1];
    const float* b1  = (const float*)d_in[2];
    const float* W2  = (const float*)d_in[3];
    const float* b2  = (const float*)d_in[4];
    const float* Wo  = (const float*)d_in[5];
    const float* bo  = (const float*)d_in[6];
    float* out = (float*)d_out;
    const int B = in_sizes[0] / (NA * 32);
    hipLaunchKernelGGL(gnn_fused, dim3(B), dim3(512), 0, stream,
                       obs, W1, b1, W2, b2, Wo, bo, out);
}

// Round 12
// 31.887 us; speedup vs baseline: 1.7866x; 1.0052x over previous
//
#include <hip/hip_runtime.h>

#define NA 128   // agents per batch
#define NKN 16   // neighbours
#define NCAND 20 // candidate cap (bisect window [17,20])

typedef _Float16 f16;
typedef __fp16   h16x2 __attribute__((ext_vector_type(2)));   // cvt_pkrtz result type
typedef _Float16 f16x8 __attribute__((ext_vector_type(8)));
typedef float    f32x16 __attribute__((ext_vector_type(16)));
typedef unsigned long long u64;

#define MFMA __builtin_amdgcn_mfma_f32_32x32x16_f16
// 256B-row f16 matrices: XOR row bits into the 16B-slot index -> 16 slots, 2-way (free)
#define SWZ16(row, byteoff) ((byteoff) ^ (((row)&15)<<4))
// 64B-row f16 matrices (X, W1T): 4 slots
#define SWZ4(row, byteoff)  ((byteoff) ^ (((row)&3)<<4))
// candidate-slot swizzle: u64 slot l of agent ia -> spread 16 agents across banks
#define CSW(ia, l) ((l) ^ (((ia) & 15) << 1))

__device__ __forceinline__ float tanh_fast(float x){
    float e = __expf(2.f * x);
    return 1.f - 2.f * __builtin_amdgcn_rcpf(e + 1.f);
}

__device__ __forceinline__ unsigned int wsel(const uint4 c, int i){ // i compile-time
    return i==0 ? c.x : i==1 ? c.y : i==2 ? c.z : c.w;
}

// OUT[h][j] = sum_i IN[h][i]*M[i][j] (M incl. diagonal); X = tanh(d_j*OUT + bias[h]) stored-T.
__device__ __forceinline__ void agg_mm(const unsigned char* matIn, unsigned char* matOut,
                                       const unsigned int (*cmask)[4], const float* dinv_s,
                                       const float* bias, const u64* lut,
                                       int wv, int lane)
{
    const int lr = lane & 31, lg = lane >> 5;
    const int rb = wv & 3, ch = wv >> 2;
    f32x16 c0, c1;
    #pragma unroll
    for (int e = 0; e < 16; ++e) { c0[e] = 0.f; c1[e] = 0.f; }

    const int j0 = ch*64 + lr, j1 = j0 + 32;
    const uint4 cm0 = *(const uint4*)&cmask[j0][0];
    const uint4 cm1 = *(const uint4*)&cmask[j1][0];
    const int row = rb*32 + lr;   // h

    __builtin_amdgcn_s_setprio(1);
    #pragma unroll
    for (int ks = 0; ks < 8; ++ks) {
        f16x8 af = *(const f16x8*)(matIn + row*256 + SWZ16(row, ks*32 + lg*16));
        const int sh = (ks&1)*16 + lg*8;
        const unsigned int b0 = (wsel(cm0, ks>>1) >> sh) & 0xFFu;
        const unsigned int b1 = (wsel(cm1, ks>>1) >> sh) & 0xFFu;
        union { f16x8 v; u64 u[2]; } B0, B1;
        B0.u[0] = lut[b0 & 15u]; B0.u[1] = lut[b0 >> 4];
        B1.u[0] = lut[b1 & 15u]; B1.u[1] = lut[b1 >> 4];
        c0 = MFMA(af, B0.v, c0, 0, 0, 0);
        c1 = MFMA(af, B1.v, c1, 0, 0, 0);
    }
    __builtin_amdgcn_s_setprio(0);
    #pragma unroll
    for (int ct = 0; ct < 2; ++ct) {
        const int j = ct ? j1 : j0;
        const float dj = dinv_s[j];
        #pragma unroll
        for (int q = 0; q < 4; ++q) {
            const int r0 = rb*32 + q*8 + lg*4;   // h quad
            const float4 bv = *(const float4*)&bias[r0];
            float v0, v1, v2, v3;
            if (ct == 0) {
                v0 = tanh_fast(fmaf(dj, c0[q*4+0], bv.x));
                v1 = tanh_fast(fmaf(dj, c0[q*4+1], bv.y));
                v2 = tanh_fast(fmaf(dj, c0[q*4+2], bv.z));
                v3 = tanh_fast(fmaf(dj, c0[q*4+3], bv.w));
            } else {
                v0 = tanh_fast(fmaf(dj, c1[q*4+0], bv.x));
                v1 = tanh_fast(fmaf(dj, c1[q*4+1], bv.y));
                v2 = tanh_fast(fmaf(dj, c1[q*4+2], bv.z));
                v3 = tanh_fast(fmaf(dj, c1[q*4+3], bv.w));
            }
            union { h16x2 h[2]; u64 u; } pk;
            pk.h[0] = __builtin_amdgcn_cvt_pkrtz(v0, v1);
            pk.h[1] = __builtin_amdgcn_cvt_pkrtz(v2, v3);
            *(u64*)(matOut + j*256 + SWZ16(j, r0*2)) = pk.u;
        }
    }
}

__global__ __launch_bounds__(512, 4) void gnn_fused(
    const float* __restrict__ obs,
    const float* __restrict__ W1g, const float* __restrict__ b1g,
    const float* __restrict__ W2g, const float* __restrict__ b2g,
    const float* __restrict__ Wog, const float* __restrict__ bog,
    float* __restrict__ outg)
{
    __shared__ __align__(16) unsigned char mat0[32768]; // cand -> G1 -> W2T -> head partials
    __shared__ __align__(16) unsigned char mat1[32768]; // Xf16(8K) -> X2 -> G2
    __shared__ __align__(16) unsigned char w1t[8192];   // W1T image (own buffer)
    __shared__ float posx[NA], posy[NA], dinv_s[NA], b1s[NA], b2s[NA], wos[NA];
    __shared__ unsigned int cmask[NA][4];
    __shared__ u64 lut16[16];

    const int t = threadIdx.x;
    const int b = blockIdx.x;
    const int wv = t >> 6, lane = t & 63;
    const int lr = lane & 31, lg = lane >> 5;

    // ---- phase 0: stage obs->Xf16 (+pos), W1T, params, cmask diag, LUT, cand init ----
    const int ia = t >> 2, p4 = t & 3;
    {
        const float4* ob = (const float4*)(obs + (size_t)b * NA * 32);
        #pragma unroll
        for (int rep = 0; rep < 2; ++rep) {
            const int idx = rep*512 + t;         // 1024 float4 = [128 i][8 seg]
            const int i = idx >> 3, seg = idx & 7;
            const float4 v = ob[idx];
            if (seg == 0) { posx[i] = v.x; posy[i] = v.y; }
            union { h16x2 h[2]; u64 u; } pk;
            pk.h[0] = __builtin_amdgcn_cvt_pkrtz(v.x, v.y);
            pk.h[1] = __builtin_amdgcn_cvt_pkrtz(v.z, v.w);
            *(u64*)(mat1 + i*64 + SWZ4(i, seg*8)) = pk.u;
        }
        {   // W1T tile per thread: h = t&127, g = t>>7 (coalesced over h)
            const int h = t & 127, g = t >> 7;
            f16x8 v;
            #pragma unroll
            for (int s = 0; s < 8; ++s) v[s] = (f16)W1g[(g*8 + s)*128 + h];   // RTN cvt
            *(f16x8*)(w1t + h*64 + SWZ4(h, g*16)) = v;
        }
        u64* cand = (u64*)mat0;                  // live slots [0,NCAND) per agent
        #pragma unroll
        for (int q = 0; q < 5; ++q) cand[ia*32 + CSW(ia, 5*p4 + q)] = ~0ull;
        if (t < NA) { b1s[t] = b1g[t]; b2s[t] = b2g[t]; wos[t] = Wog[t]; }
        { const int j = t >> 2, w = t & 3; cmask[j][w] = (w == (j>>5)) ? (1u << (j&31)) : 0u; }
        if (t < 16) {
            u64 e = 0ull;
            #pragma unroll
            for (int s = 0; s < 4; ++s)
                if ((t >> s) & 1) e |= 0x3C00ull << (16*s);   // f16 1.0
            lut16[t] = e;
        }
    }
    __syncthreads();

    // ---- phase 1: exact kNN via pivot-bisection (window [17,20]) + prefix compaction ----
    int mtot;
    {
        u64* cand = (u64*)mat0;
        // 1a: distance bit-keys (bit-exact vs ref: rn mul/add, rn sqrt; monotone u32)
        unsigned int kd[32];
        const float xi = posx[ia], yi = posy[ia];
        #pragma unroll
        for (int jj = 0; jj < 32; ++jj) {
            const int j = p4*32 + jj;
            const float dx = __fsub_rn(xi, posx[j]);
            const float dy = __fsub_rn(yi, posy[j]);
            const float d  = __fsqrt_rn(__fadd_rn(__fmul_rn(dx,dx), __fmul_rn(dy,dy)));
            kd[jj] = __float_as_uint(d);         // self: exactly 0
        }
        // 1b: bisect pivot P until 17 <= count(kd < P) <= NCAND
        unsigned int lo = 0u, hi = 0xFF000000u, P = 0u;
        bool done = false;
        #pragma unroll 1
        for (int it = 0; it < 34; ++it) {
            const unsigned int mid = (lo + hi) >> 1;
            int cl = 0;
            #pragma unroll
            for (int jj = 0; jj < 32; ++jj) cl += (kd[jj] < mid) ? 1 : 0;
            cl += __shfl_xor(cl, 1, 64);
            cl += __shfl_xor(cl, 2, 64);
            if (!done) {
                if (cl >= 17 && cl <= NCAND) { P = mid; done = true; }
                else if (cl < 17) lo = mid;
                else hi = mid;
                if (hi - lo <= 1u && !done) { P = hi; done = true; }
            }
            if (__all(done ? 1 : 0)) break;
        }
        if (!done) P = hi;
        // 1c: compaction via parallel popc-prefix (no serial slot chain, no atomics)
        unsigned int maskp = 0u;
        #pragma unroll
        for (int jj = 0; jj < 32; ++jj) maskp |= (kd[jj] < P) ? (1u << jj) : 0u;
        const int cnt = __popc(maskp);
        const int base = lane & ~3;
        const int c0n = __shfl(cnt, base + 0, 64);
        const int c1n = __shfl(cnt, base + 1, 64);
        const int c2n = __shfl(cnt, base + 2, 64);
        const int c3n = __shfl(cnt, base + 3, 64);
        mtot = c0n + c1n + c2n + c3n;
        const int pbase = (p4 > 0 ? c0n : 0) + (p4 > 1 ? c1n : 0) + (p4 > 2 ? c2n : 0);
        #pragma unroll
        for (int jj = 0; jj < 32; ++jj) {
            if ((maskp >> jj) & 1u) {
                const int slot = pbase + __popc(maskp & ((1u << jj) - 1u));
                if (slot < NCAND)
                    cand[ia*32 + CSW(ia, slot)] = ((u64)kd[jj] << 32) | (unsigned)(p4*32 + jj);
            }
        }
    }
    __syncthreads();
    {
        const u64* cand = (const u64*)mat0;
        // 1d: rank among <=20 candidates (exact (dist,idx) lexicographic order).
        // rank r in [1,16] => neighbor (rank 0 = the dropped first top_k entry, exactly
        // matching top_k(-d,17)[1:] incl. duplicate-position degeneracy).
        // STATIC register indexing only (rule #20): lane owns 5 candidates.
        u64 ck5[5];
        int rk[5];
        #pragma unroll
        for (int q = 0; q < 5; ++q) {
            ck5[q] = cand[ia*32 + CSW(ia, 5*p4 + q)];
            rk[q] = 0;
        }
        #pragma unroll
        for (int e = 0; e < NCAND; ++e) {
            const u64 ke = cand[ia*32 + CSW(ia, e)];
            #pragma unroll
            for (int q = 0; q < 5; ++q) rk[q] += (ke < ck5[q]) ? 1 : 0;
        }
        const int m = min(mtot, NCAND);
        #pragma unroll
        for (int q = 0; q < 5; ++q) {
            const int c = 5*p4 + q;
            if (c < m && rk[q] >= 1 && rk[q] < 17) {
                const int n = (int)(ck5[q] & 127u);
                atomicOr(&cmask[n][ia >> 5], 1u << (ia & 31));
            }
        }
    }
    __syncthreads();
    // ---- degrees (needs complete cmask; barrier before conv1 epilogue reads dinv) ----
    if (t < NA)
        dinv_s[t] = rsqrtf((float)(__popc(cmask[t][0]) + __popc(cmask[t][1]) +
                                   __popc(cmask[t][2]) + __popc(cmask[t][3])));
    __syncthreads();

    // ---- phase 2: conv1  G1[h][i] = d_i*(X@W1)[i][h]; no mid-barrier (W1T separate) ----
    {
        f32x16 c0, c1;
        #pragma unroll
        for (int e = 0; e < 16; ++e) { c0[e] = 0.f; c1[e] = 0.f; }
        const int rb = wv & 3, ch = wv >> 2;
        const int row = rb*32 + lr;              // node i
        #pragma unroll
        for (int ks = 0; ks < 2; ++ks) {
            const f16x8 af = *(const f16x8*)(mat1 + row*64 + SWZ4(row, ks*32 + lg*16));
            #pragma unroll
            for (int ct = 0; ct < 2; ++ct) {
                const int h = ch*64 + ct*32 + lr;
                const f16x8 bf = *(const f16x8*)(w1t + h*64 + SWZ4(h, ks*32 + lg*16));
                if (ct == 0) c0 = MFMA(af, bf, c0, 0, 0, 0);
                else         c1 = MFMA(af, bf, c1, 0, 0, 0);
            }
        }
        // epilogue writes G1 into mat0 (cand dead since rank barrier) -- no barrier needed
        #pragma unroll
        for (int ct = 0; ct < 2; ++ct) {
            const int h = ch*64 + ct*32 + lr;
            #pragma unroll
            for (int q = 0; q < 4; ++q) {
                const int r0 = rb*32 + q*8 + lg*4;   // node quad
                const float4 dv = *(const float4*)&dinv_s[r0];
                union { h16x2 hh[2]; u64 u; } pk;
                if (ct == 0) {
                    pk.hh[0] = __builtin_amdgcn_cvt_pkrtz(c0[q*4+0]*dv.x, c0[q*4+1]*dv.y);
                    pk.hh[1] = __builtin_amdgcn_cvt_pkrtz(c0[q*4+2]*dv.z, c0[q*4+3]*dv.w);
                } else {
                    pk.hh[0] = __builtin_amdgcn_cvt_pkrtz(c1[q*4+0]*dv.x, c1[q*4+1]*dv.y);
                    pk.hh[1] = __builtin_amdgcn_cvt_pkrtz(c1[q*4+2]*dv.z, c1[q*4+3]*dv.w);
                }
                *(u64*)(mat0 + h*256 + SWZ16(h, r0*2)) = pk.u;
            }
        }
    }
    // ---- T14: issue W2 global loads now; consumed after agg1 (latency hides under MFMA) ----
    float w2r[32];
    #pragma unroll
    for (int r = 0; r < 4; ++r) {
        const int idx = r*512 + t, h2 = idx & 127, g = idx >> 7;
        #pragma unroll
        for (int s = 0; s < 8; ++s) w2r[r*8 + s] = W2g[(g*8 + s)*128 + h2];
    }
    __syncthreads();

    // ---- phase 3: agg1 -> X2[j][h] in mat1 ----
    agg_mm(mat0, mat1, cmask, dinv_s, b1s, lut16, wv, lane);
    __syncthreads();

    // ---- phase 4: store W2T f16 image to mat0 (RTN cvt from regs), then conv2 ----
    {
        #pragma unroll
        for (int r = 0; r < 4; ++r) {
            const int idx = r*512 + t, h2 = idx & 127, g = idx >> 7;
            f16x8 v;
            #pragma unroll
            for (int s = 0; s < 8; ++s) v[s] = (f16)w2r[r*8 + s];   // RTN cvt
            *(f16x8*)(mat0 + h2*256 + SWZ16(h2, g*16)) = v;
        }
    }
    __syncthreads();
    {
        f32x16 c0, c1;
        #pragma unroll
        for (int e = 0; e < 16; ++e) { c0[e] = 0.f; c1[e] = 0.f; }
        const int rb = wv & 3, ch = wv >> 2;
        const int row = rb*32 + lr;              // j
        __builtin_amdgcn_s_setprio(1);
        #pragma unroll
        for (int ks = 0; ks < 8; ++ks) {
            const f16x8 af = *(const f16x8*)(mat1 + row*256 + SWZ16(row, ks*32 + lg*16));
            #pragma unroll
            for (int ct = 0; ct < 2; ++ct) {
                const int h2 = ch*64 + ct*32 + lr;
                const f16x8 bf = *(const f16x8*)(mat0 + h2*256 + SWZ16(h2, ks*32 + lg*16));
                if (ct == 0) c0 = MFMA(af, bf, c0, 0, 0, 0);
                else         c1 = MFMA(af, bf, c1, 0, 0, 0);
            }
        }
        __builtin_amdgcn_s_setprio(0);
        __syncthreads();   // X2/W2T reads done before G2 overwrites mat1
        #pragma unroll
        for (int ct = 0; ct < 2; ++ct) {
            const int h2 = ch*64 + ct*32 + lr;
            #pragma unroll
            for (int q = 0; q < 4; ++q) {
                const int r0 = rb*32 + q*8 + lg*4;   // j quad
                const float4 dv = *(const float4*)&dinv_s[r0];
                union { h16x2 hh[2]; u64 u; } pk;
                if (ct == 0) {
                    pk.hh[0] = __builtin_amdgcn_cvt_pkrtz(c0[q*4+0]*dv.x, c0[q*4+1]*dv.y);
                    pk.hh[1] = __builtin_amdgcn_cvt_pkrtz(c0[q*4+2]*dv.z, c0[q*4+3]*dv.w);
                } else {
                    pk.hh[0] = __builtin_amdgcn_cvt_pkrtz(c1[q*4+0]*dv.x, c1[q*4+1]*dv.y);
                    pk.hh[1] = __builtin_amdgcn_cvt_pkrtz(c1[q*4+2]*dv.z, c1[q*4+3]*dv.w);
                }
                *(u64*)(mat1 + h2*256 + SWZ16(h2, r0*2)) = pk.u;
            }
        }
    }
    __syncthreads();

    // ---- phase 5: agg2 + FUSED head: partial dot with wo in-register, no X3 store ----
    {
        const int rb = wv & 3, ch = wv >> 2;
        f32x16 c0, c1;
        #pragma unroll
        for (int e = 0; e < 16; ++e) { c0[e] = 0.f; c1[e] = 0.f; }
        const int j0 = ch*64 + lr, j1 = j0 + 32;
        const uint4 cm0 = *(const uint4*)&cmask[j0][0];
        const uint4 cm1 = *(const uint4*)&cmask[j1][0];
        const int row = rb*32 + lr;   // h2
        __builtin_amdgcn_s_setprio(1);
        #pragma unroll
        for (int ks = 0; ks < 8; ++ks) {
            f16x8 af = *(const f16x8*)(mat1 + row*256 + SWZ16(row, ks*32 + lg*16));
            const int sh = (ks&1)*16 + lg*8;
            const unsigned int b0m = (wsel(cm0, ks>>1) >> sh) & 0xFFu;
            const unsigned int b1m = (wsel(cm1, ks>>1) >> sh) & 0xFFu;
            union { f16x8 v; u64 u[2]; } B0, B1;
            B0.u[0] = lut16[b0m & 15u]; B0.u[1] = lut16[b0m >> 4];
            B1.u[0] = lut16[b1m & 15u]; B1.u[1] = lut16[b1m >> 4];
            c0 = MFMA(af, B0.v, c0, 0, 0, 0);
            c1 = MFMA(af, B1.v, c1, 0, 0, 0);
        }
        __builtin_amdgcn_s_setprio(0);
        float* acc = (float*)mat0;   // [128 j][8 (rb*2+lg)] partials; W2T dead after conv2-end
        #pragma unroll
        for (int ct = 0; ct < 2; ++ct) {
            const int j = ct ? j1 : j0;
            const float dj = dinv_s[j];
            float part = 0.f;
            #pragma unroll
            for (int q = 0; q < 4; ++q) {
                const int r0 = rb*32 + q*8 + lg*4;   // h2 quad
                const float4 bv = *(const float4*)&b2s[r0];
                const float4 wq = *(const float4*)&wos[r0];
                float v0, v1, v2, v3;
                if (ct == 0) {
                    v0 = tanh_fast(fmaf(dj, c0[q*4+0], bv.x));
                    v1 = tanh_fast(fmaf(dj, c0[q*4+1], bv.y));
                    v2 = tanh_fast(fmaf(dj, c0[q*4+2], bv.z));
                    v3 = tanh_fast(fmaf(dj, c0[q*4+3], bv.w));
                } else {
                    v0 = tanh_fast(fmaf(dj, c1[q*4+0], bv.x));
                    v1 = tanh_fast(fmaf(dj, c1[q*4+1], bv.y));
                    v2 = tanh_fast(fmaf(dj, c1[q*4+2], bv.z));
                    v3 = tanh_fast(fmaf(dj, c1[q*4+3], bv.w));
                }
                part = fmaf(v0, wq.x, part); part = fmaf(v1, wq.y, part);
                part = fmaf(v2, wq.z, part); part = fmaf(v3, wq.w, part);
            }
            acc[j*8 + rb*2 + lg] = part;
        }
    }
    __syncthreads();
    if (t < NA) {
        const float4 a0 = *((const float4*)mat0 + t*2);
        const float4 a1 = *((const float4*)mat0 + t*2 + 1);
        const float s = ((a0.x + a0.y) + (a0.z + a0.w)) + ((a1.x + a1.y) + (a1.z + a1.w));
        outg[b*NA + t] = s + bog[0];
    }
}

extern "C" void kernel_launch(void* const* d_in, const int* in_sizes, int n_in,
                              void* d_out, int out_size, void* d_ws, size_t ws_size,
                              hipStream_t stream) {
    const float* obs = (const float*)d_in[0];
    const float* W1  = (const float*)d_in[1];
    const float* b1  = (const float*)d_in[2];
    const float* W2  = (const float*)d_in[3];
    const float* b2  = (const float*)d_in[4];
    const float* Wo  = (const float*)d_in[5];
    const float* bo  = (const float*)d_in[6];
    float* out = (float*)d_out;
    const int B = in_sizes[0] / (NA * 32);
    hipLaunchKernelGGL(gnn_fused, dim3(B), dim3(512), 0, stream,
                       obs, W1, b1, W2, b2, Wo, bo, out);
}